// Round 1
// baseline (251.156 us; speedup 1.0000x reference)
//
#include <hip/hip_runtime.h>
#include <hip/hip_bf16.h>
#include <math.h>

#define DIM 1024
#define NHEADS 16
#define HD 64
#define WIN 256
#define NB 16
#define NSEQ 4096
#define NACC 512
#define LCTX 769      // 1 + 512 + 256
#define MROWS 12304   // 16*769
#define MPAD 12416    // 97*128
#define NKV 2048

typedef short bf16x8 __attribute__((ext_vector_type(8)));
typedef float f32x4 __attribute__((ext_vector_type(4)));

__device__ inline unsigned short f2b(float f) {
    union { float f; unsigned int u; } c; c.f = f;
    unsigned int u = c.u;
    u += 0x7FFFu + ((u >> 16) & 1u);
    return (unsigned short)(u >> 16);
}
__device__ inline float b2f(unsigned short h) {
    union { unsigned int u; float f; } c; c.u = ((unsigned int)h) << 16;
    return c.f;
}

// ---------------------------------------------------------------------------
// Kernel 1: build ctx rows, LN1 -> normed (bf16), write new_acc, save ctx row 0
// grid: MPAD blocks (blocks >= MROWS zero-pad normed for the GEMM), 256 thr
// ---------------------------------------------------------------------------
__global__ __launch_bounds__(256) void build_ln_kernel(
    const float* __restrict__ x, const float* __restrict__ state,
    const float* __restrict__ acc_ctx, const int* __restrict__ fix_pt,
    const float* __restrict__ ln1_g, const float* __restrict__ ln1_b,
    unsigned short* __restrict__ normed, float* __restrict__ ctx0,
    float* __restrict__ newacc)
{
    int bid = blockIdx.x;
    int t = threadIdx.x;
    if (bid >= MROWS) {
        ushort4 z = make_ushort4(0, 0, 0, 0);
        ((ushort4*)(normed + (size_t)bid * DIM))[t] = z;
        return;
    }
    int b = bid / LCTX;
    int r = bid - b * LCTX;
    const float* src;
    if (r == 0) {
        src = state + (size_t)b * DIM;
    } else if (r <= NACC) {
        src = acc_ctx + ((size_t)b * NACC + (r - 1)) * DIM;
    } else {
        int fp = fix_pt[b];
        int start = fp - WIN / 2;
        if (start < 0) start = 0;
        if (start > NSEQ - WIN) start = NSEQ - WIN;
        src = x + ((size_t)b * NSEQ + start + (r - 1 - NACC)) * DIM;
    }
    float4 v = ((const float4*)src)[t];
    float s = v.x + v.y + v.z + v.w;
    float ss = v.x * v.x + v.y * v.y + v.z * v.z + v.w * v.w;
#pragma unroll
    for (int o = 32; o > 0; o >>= 1) { s += __shfl_down(s, o); ss += __shfl_down(ss, o); }
    __shared__ float rs[4], rss[4];
    int wid = t >> 6, lane = t & 63;
    if (lane == 0) { rs[wid] = s; rss[wid] = ss; }
    __syncthreads();
    float sum = rs[0] + rs[1] + rs[2] + rs[3];
    float sq  = rss[0] + rss[1] + rss[2] + rss[3];
    float mean = sum * (1.0f / DIM);
    float var = sq * (1.0f / DIM) - mean * mean;
    float rstd = rsqrtf(var + 1e-5f);
    float4 g  = ((const float4*)ln1_g)[t];
    float4 be = ((const float4*)ln1_b)[t];
    ushort4 nb;
    nb.x = f2b((v.x - mean) * rstd * g.x + be.x);
    nb.y = f2b((v.y - mean) * rstd * g.y + be.y);
    nb.z = f2b((v.z - mean) * rstd * g.z + be.z);
    nb.w = f2b((v.w - mean) * rstd * g.w + be.w);
    ((ushort4*)(normed + (size_t)bid * DIM))[t] = nb;
    if (r == 0) {
        ((float4*)(ctx0 + (size_t)b * DIM))[t] = v;
    } else {
        ((float4*)(newacc + ((size_t)b * (LCTX - 1) + (r - 1)) * DIM))[t] = v;
    }
}

// ---------------------------------------------------------------------------
// Kernel 2: convert in_proj_w (3072x1024 f32) -> bf16
// ---------------------------------------------------------------------------
__global__ __launch_bounds__(256) void convert_w_kernel(
    const float* __restrict__ w, unsigned short* __restrict__ wb, int n4)
{
    int idx = blockIdx.x * 256 + threadIdx.x;
    if (idx >= n4) return;
    float4 v = ((const float4*)w)[idx];
    ushort4 o;
    o.x = f2b(v.x); o.y = f2b(v.y); o.z = f2b(v.z); o.w = f2b(v.w);
    ((ushort4*)wb)[idx] = o;
}

// ---------------------------------------------------------------------------
// Kernel 3: KV GEMM  C[m,n] = sum_k A[m,k]*Bw[n,k] + bias[n]
// A: MPAD x 1024 bf16 (normed, padded), Bw: 2048 x 1024 bf16 (Wk;Wv rows)
// m97 structure: 128x128 tile, BK=64, 4 waves, global_load_lds width 16
// ---------------------------------------------------------------------------
__global__ __launch_bounds__(256) void kv_gemm_kernel(
    const unsigned short* __restrict__ A,
    const unsigned short* __restrict__ Bw,
    const float* __restrict__ bias,
    unsigned short* __restrict__ C)
{
    __shared__ unsigned short As[128 * 64];
    __shared__ unsigned short Bs[128 * 64];
    int mt = blockIdx.x, nt = blockIdx.y;
    int t = threadIdx.x;
    int w = t >> 6, lane = t & 63;
    int wm = w >> 1, wn = w & 1;
    f32x4 acc[4][4] = {};
    const size_t abase = (size_t)mt * 128 * 1024;
    const size_t bbase = (size_t)nt * 128 * 1024;
    for (int kt = 0; kt < 16; ++kt) {
        int k0 = kt * 64;
#pragma unroll
        for (int i = 0; i < 4; ++i) {
            int c = i * 256 + t;
            int row = c >> 3, cc = c & 7;
            const unsigned short* ga = A + abase + (size_t)row * 1024 + k0 + cc * 8;
            const unsigned short* gb = Bw + bbase + (size_t)row * 1024 + k0 + cc * 8;
            __builtin_amdgcn_global_load_lds(
                (const __attribute__((address_space(1))) void*)ga,
                (__attribute__((address_space(3))) void*)&As[c * 8], 16, 0, 0);
            __builtin_amdgcn_global_load_lds(
                (const __attribute__((address_space(1))) void*)gb,
                (__attribute__((address_space(3))) void*)&Bs[c * 8], 16, 0, 0);
        }
        __syncthreads();
#pragma unroll
        for (int ks = 0; ks < 2; ++ks) {
            bf16x8 af[4], bfr[4];
#pragma unroll
            for (int i = 0; i < 4; ++i) {
                int ar = wm * 64 + i * 16 + (lane & 15);
                int col = ks * 32 + (lane >> 4) * 8;
                af[i] = *(const bf16x8*)&As[ar * 64 + col];
                int br = wn * 64 + i * 16 + (lane & 15);
                bfr[i] = *(const bf16x8*)&Bs[br * 64 + col];
            }
#pragma unroll
            for (int i = 0; i < 4; ++i)
#pragma unroll
                for (int j = 0; j < 4; ++j)
                    acc[i][j] = __builtin_amdgcn_mfma_f32_16x16x32_bf16(
                        af[i], bfr[j], acc[i][j], 0, 0, 0);
        }
        __syncthreads();
    }
#pragma unroll
    for (int i = 0; i < 4; ++i) {
#pragma unroll
        for (int r = 0; r < 4; ++r) {
            int gm = mt * 128 + wm * 64 + i * 16 + (lane >> 4) * 4 + r;
            if (gm >= MROWS) continue;
#pragma unroll
            for (int j = 0; j < 4; ++j) {
                int gn = nt * 128 + wn * 64 + j * 16 + (lane & 15);
                C[(size_t)gm * NKV + gn] = f2b(acc[i][j][r] + bias[gn]);
            }
        }
    }
}

// ---------------------------------------------------------------------------
// Kernel 4: q0[b,d] = sum_k normed[b,0,k]*Wq[d,k] + bq[d]  (wave per output)
// grid: 4096 blocks x 4 waves = 16384 outputs
// ---------------------------------------------------------------------------
__global__ __launch_bounds__(256) void q_proj_kernel(
    const unsigned short* __restrict__ normed, const unsigned short* __restrict__ Wb,
    const float* __restrict__ bias, float* __restrict__ q0)
{
    int gw = blockIdx.x * 4 + (threadIdx.x >> 6);
    int lane = threadIdx.x & 63;
    int b = gw >> 10, d = gw & 1023;
    const unsigned short* nr = normed + (size_t)(b * LCTX) * DIM;
    const unsigned short* wr = Wb + (size_t)d * DIM;
    float s = 0.f;
#pragma unroll
    for (int kk = 0; kk < 16; ++kk) {
        int k = kk * 64 + lane;
        s += b2f(nr[k]) * b2f(wr[k]);
    }
#pragma unroll
    for (int o = 32; o > 0; o >>= 1) s += __shfl_down(s, o);
    if (lane == 0) q0[gw] = s + bias[d];
}

// ---------------------------------------------------------------------------
// Kernel 5: attention decode, one block per (b,h): 769 keys, softmax, PV
// ---------------------------------------------------------------------------
__global__ __launch_bounds__(256) void attn_kernel(
    const float* __restrict__ q0, const unsigned short* __restrict__ kv,
    float* __restrict__ o_all)
{
    int b = blockIdx.x >> 4, h = blockIdx.x & 15;
    int t = threadIdx.x;
    __shared__ float qs[64];
    __shared__ float sc[LCTX];
    __shared__ float red1[4], red2[4];
    __shared__ float po[4][64];
    if (t < 64) qs[t] = q0[b * 1024 + h * 64 + t];
    __syncthreads();
    float lmax = -1e30f;
    for (int l = t; l < LCTX; l += 256) {
        const unsigned short* kr = kv + ((size_t)(b * LCTX + l)) * NKV + h * 64;
        const uint4* k4 = (const uint4*)kr;
        float s = 0.f;
#pragma unroll
        for (int c = 0; c < 8; ++c) {
            uint4 u = k4[c];
            s += qs[c * 8 + 0] * b2f((unsigned short)(u.x & 0xffffu));
            s += qs[c * 8 + 1] * b2f((unsigned short)(u.x >> 16));
            s += qs[c * 8 + 2] * b2f((unsigned short)(u.y & 0xffffu));
            s += qs[c * 8 + 3] * b2f((unsigned short)(u.y >> 16));
            s += qs[c * 8 + 4] * b2f((unsigned short)(u.z & 0xffffu));
            s += qs[c * 8 + 5] * b2f((unsigned short)(u.z >> 16));
            s += qs[c * 8 + 6] * b2f((unsigned short)(u.w & 0xffffu));
            s += qs[c * 8 + 7] * b2f((unsigned short)(u.w >> 16));
        }
        s *= 0.125f;
        sc[l] = s;
        lmax = fmaxf(lmax, s);
    }
#pragma unroll
    for (int o = 32; o > 0; o >>= 1) lmax = fmaxf(lmax, __shfl_down(lmax, o));
    int wid = t >> 6, lane = t & 63;
    if (lane == 0) red1[wid] = lmax;
    __syncthreads();
    float m = fmaxf(fmaxf(red1[0], red1[1]), fmaxf(red1[2], red1[3]));
    float lsum = 0.f;
    for (int l = t; l < LCTX; l += 256) {
        float p = __expf(sc[l] - m);
        sc[l] = p;
        lsum += p;
    }
#pragma unroll
    for (int o = 32; o > 0; o >>= 1) lsum += __shfl_down(lsum, o);
    if (lane == 0) red2[wid] = lsum;
    __syncthreads();
    float S = red2[0] + red2[1] + red2[2] + red2[3];
    int d = t & 63, ls = t >> 6;
    float a = 0.f;
    for (int l = ls; l < LCTX; l += 4) {
        const unsigned short* vr = kv + ((size_t)(b * LCTX + l)) * NKV + 1024 + h * 64;
        a += sc[l] * b2f(vr[d]);
    }
    po[ls][d] = a;
    __syncthreads();
    if (t < 64) {
        float o = (po[0][t] + po[1][t] + po[2][t] + po[3][t]) / S;
        o_all[b * 1024 + h * 64 + t] = o;
    }
}

// ---------------------------------------------------------------------------
// Kernel 6: cls_pre[b,i] = ctx0[b,i] + sum_j o_all[b,j]*out_w[i,j] + out_b[i]
// ---------------------------------------------------------------------------
__global__ __launch_bounds__(256) void out_proj_kernel(
    const float* __restrict__ o_all, const float* __restrict__ out_w,
    const float* __restrict__ out_b, const float* __restrict__ ctx0,
    float* __restrict__ cls_pre)
{
    int gw = blockIdx.x * 4 + (threadIdx.x >> 6);
    int lane = threadIdx.x & 63;
    int b = gw >> 10, i = gw & 1023;
    const float* orow = o_all + (size_t)b * 1024;
    const float* wrow = out_w + (size_t)i * 1024;
    float s = 0.f;
#pragma unroll
    for (int kk = 0; kk < 16; ++kk) {
        int k = kk * 64 + lane;
        s += orow[k] * wrow[k];
    }
#pragma unroll
    for (int o = 32; o > 0; o >>= 1) s += __shfl_down(s, o);
    if (lane == 0) cls_pre[gw] = ctx0[gw] + s + out_b[i];
}

// ---------------------------------------------------------------------------
// Kernel 7: LN2 over cls_pre rows
// ---------------------------------------------------------------------------
__global__ __launch_bounds__(256) void ln2_kernel(
    const float* __restrict__ cls_pre, const float* __restrict__ g,
    const float* __restrict__ be, float* __restrict__ ln2o)
{
    int b = blockIdx.x, t = threadIdx.x;
    float4 v = ((const float4*)(cls_pre + (size_t)b * DIM))[t];
    float s = v.x + v.y + v.z + v.w;
    float ss = v.x * v.x + v.y * v.y + v.z * v.z + v.w * v.w;
#pragma unroll
    for (int o = 32; o > 0; o >>= 1) { s += __shfl_down(s, o); ss += __shfl_down(ss, o); }
    __shared__ float rs[4], rss[4];
    int wid = t >> 6, lane = t & 63;
    if (lane == 0) { rs[wid] = s; rss[wid] = ss; }
    __syncthreads();
    float sum = rs[0] + rs[1] + rs[2] + rs[3];
    float sq  = rss[0] + rss[1] + rss[2] + rss[3];
    float mean = sum * (1.0f / DIM);
    float var = sq * (1.0f / DIM) - mean * mean;
    float rstd = rsqrtf(var + 1e-5f);
    float4 gv = ((const float4*)g)[t];
    float4 bv = ((const float4*)be)[t];
    float4 o;
    o.x = (v.x - mean) * rstd * gv.x + bv.x;
    o.y = (v.y - mean) * rstd * gv.y + bv.y;
    o.z = (v.z - mean) * rstd * gv.z + bv.z;
    o.w = (v.w - mean) * rstd * gv.w + bv.w;
    ((float4*)(ln2o + (size_t)b * DIM))[t] = o;
}

// ---------------------------------------------------------------------------
// Kernel 8: h = gelu(ln2 @ w1 + b1); block = (j-chunk of 32) x (8 batches)
// w1 read exactly once from HBM across the grid
// ---------------------------------------------------------------------------
__global__ __launch_bounds__(256) void mlp1_kernel(
    const float* __restrict__ ln2v, const float* __restrict__ w1,
    const float* __restrict__ b1, float* __restrict__ h)
{
    __shared__ float l2s[8][1024];
    __shared__ float part[8][32][8];
    int jc = blockIdx.x;   // 0..127
    int bh = blockIdx.y;   // 0..1
    int t = threadIdx.x;
    const float4* src = (const float4*)(ln2v + (size_t)bh * 8 * 1024);
#pragma unroll
    for (int i = 0; i < 8; ++i)
        ((float4*)&l2s[0][0])[i * 256 + t] = src[i * 256 + t];
    __syncthreads();
    int jl = t & 31, ks = t >> 5;
    int j = jc * 32 + jl;
    float acc[8] = {};
    for (int kk = 0; kk < 128; ++kk) {
        int k = ks * 128 + kk;
        float wv = w1[(size_t)k * 4096 + j];
#pragma unroll
        for (int bb = 0; bb < 8; ++bb) acc[bb] += l2s[bb][k] * wv;
    }
#pragma unroll
    for (int bb = 0; bb < 8; ++bb) part[ks][jl][bb] = acc[bb];
    __syncthreads();
    int jl2 = t >> 3, bb = t & 7;
    float s = 0.f;
#pragma unroll
    for (int q = 0; q < 8; ++q) s += part[q][jl2][bb];
    int jj = jc * 32 + jl2;
    s += b1[jj];
    float ge = 0.5f * s * (1.0f + erff(s * 0.70710678118f));
    h[(size_t)(bh * 8 + bb) * 4096 + jj] = ge;
}

// ---------------------------------------------------------------------------
// Kernel 9: cls_out = cls_pre + h @ w2 + b2; block = (i-chunk 32) x (2 batches)
// ---------------------------------------------------------------------------
__global__ __launch_bounds__(256) void mlp2_kernel(
    const float* __restrict__ h, const float* __restrict__ w2,
    const float* __restrict__ b2, const float* __restrict__ cls_pre,
    float* __restrict__ outp)
{
    __shared__ float hs[2][4096];
    __shared__ float part[8][32][2];
    int ic = blockIdx.x;  // 0..31
    int bq = blockIdx.y;  // 0..7
    int t = threadIdx.x;
    const float4* src = (const float4*)(h + (size_t)bq * 2 * 4096);
#pragma unroll
    for (int i = 0; i < 8; ++i)
        ((float4*)&hs[0][0])[i * 256 + t] = src[i * 256 + t];
    __syncthreads();
    int jl = t & 31, ks = t >> 5;
    int i = ic * 32 + jl;
    float a0 = 0.f, a1 = 0.f;
    for (int kk = 0; kk < 512; ++kk) {
        int k = ks * 512 + kk;
        float wv = w2[(size_t)k * 1024 + i];
        a0 += hs[0][k] * wv;
        a1 += hs[1][k] * wv;
    }
    part[ks][jl][0] = a0;
    part[ks][jl][1] = a1;
    __syncthreads();
    if (t < 64) {
        int jl2 = t >> 1, bb = t & 1;
        float s = 0.f;
#pragma unroll
        for (int q = 0; q < 8; ++q) s += part[q][jl2][bb];
        int ii = ic * 32 + jl2;
        int bbb = bq * 2 + bb;
        outp[(size_t)bbb * 1024 + ii] = cls_pre[(size_t)bbb * 1024 + ii] + s + b2[ii];
    }
}

// ---------------------------------------------------------------------------
extern "C" void kernel_launch(void* const* d_in, const int* in_sizes, int n_in,
                              void* d_out, int out_size, void* d_ws, size_t ws_size,
                              hipStream_t stream)
{
    const float* x        = (const float*)d_in[0];
    const float* state    = (const float*)d_in[1];
    const float* acc_ctx  = (const float*)d_in[2];
    const int*   fix_pt   = (const int*)d_in[3];
    const float* in_proj_w = (const float*)d_in[4];
    const float* in_proj_b = (const float*)d_in[5];
    const float* out_w    = (const float*)d_in[6];
    const float* out_b    = (const float*)d_in[7];
    const float* ln1_g    = (const float*)d_in[8];
    const float* ln1_b    = (const float*)d_in[9];
    const float* ln2_g    = (const float*)d_in[10];
    const float* ln2_b    = (const float*)d_in[11];
    const float* w1       = (const float*)d_in[12];
    const float* b1       = (const float*)d_in[13];
    const float* w2       = (const float*)d_in[14];
    const float* b2       = (const float*)d_in[15];
    float* outp = (float*)d_out;

    char* ws = (char*)d_ws;
    unsigned short* normed = (unsigned short*)ws; ws += (size_t)MPAD * DIM * 2;
    unsigned short* Wb     = (unsigned short*)ws; ws += (size_t)3072 * DIM * 2;
    unsigned short* kvb    = (unsigned short*)ws; ws += (size_t)MROWS * NKV * 2;
    float* ctx0    = (float*)ws; ws += (size_t)NB * DIM * 4;
    float* q0      = (float*)ws; ws += (size_t)NB * DIM * 4;
    float* o_all   = (float*)ws; ws += (size_t)NB * DIM * 4;
    float* cls_pre = (float*)ws; ws += (size_t)NB * DIM * 4;
    float* ln2v    = (float*)ws; ws += (size_t)NB * DIM * 4;
    float* hbuf    = (float*)ws; ws += (size_t)NB * 4096 * 4;

    float* newacc = outp + (size_t)NB * DIM;  // output 1 starts after cls_out

    hipLaunchKernelGGL(build_ln_kernel, dim3(MPAD), dim3(256), 0, stream,
                       x, state, acc_ctx, fix_pt, ln1_g, ln1_b, normed, ctx0, newacc);
    hipLaunchKernelGGL(convert_w_kernel, dim3(3072), dim3(256), 0, stream,
                       in_proj_w, Wb, 3072 * DIM / 4);
    hipLaunchKernelGGL(kv_gemm_kernel, dim3(97, 16), dim3(256), 0, stream,
                       normed, Wb + (size_t)1024 * DIM, in_proj_b + 1024, kvb);
    hipLaunchKernelGGL(q_proj_kernel, dim3(4096), dim3(256), 0, stream,
                       normed, Wb, in_proj_b, q0);
    hipLaunchKernelGGL(attn_kernel, dim3(256), dim3(256), 0, stream,
                       q0, kvb, o_all);
    hipLaunchKernelGGL(out_proj_kernel, dim3(4096), dim3(256), 0, stream,
                       o_all, out_w, out_b, ctx0, cls_pre);
    hipLaunchKernelGGL(ln2_kernel, dim3(16), dim3(256), 0, stream,
                       cls_pre, ln2_g, ln2_b, ln2v);
    hipLaunchKernelGGL(mlp1_kernel, dim3(128, 2), dim3(256), 0, stream,
                       ln2v, w1, b1, hbuf);
    hipLaunchKernelGGL(mlp2_kernel, dim3(32, 8), dim3(256), 0, stream,
                       hbuf, w2, b2, cls_pre, outp);
}

// Round 2
// 233.553 us; speedup vs baseline: 1.0754x; 1.0754x over previous
//
#include <hip/hip_runtime.h>
#include <hip/hip_bf16.h>
#include <math.h>

#define DIM 1024
#define NHEADS 16
#define HD 64
#define WIN 256
#define NB 16
#define NSEQ 4096
#define NACC 512
#define LCTX 769      // 1 + 512 + 256
#define MROWS 12304   // 16*769
#define MPAD2 12544   // 49*256
#define NKV 2048

typedef short bf16x8 __attribute__((ext_vector_type(8)));
typedef float f32x4 __attribute__((ext_vector_type(4)));

__device__ inline unsigned short f2b(float f) {
    union { float f; unsigned int u; } c; c.f = f;
    unsigned int u = c.u;
    u += 0x7FFFu + ((u >> 16) & 1u);
    return (unsigned short)(u >> 16);
}
__device__ inline float b2f(unsigned short h) {
    union { unsigned int u; float f; } c; c.u = ((unsigned int)h) << 16;
    return c.f;
}

// ---------------------------------------------------------------------------
// Kernel 1: build ctx rows, LN1 -> normed (bf16), write new_acc, save ctx row 0
// ---------------------------------------------------------------------------
__global__ __launch_bounds__(256) void build_ln_kernel(
    const float* __restrict__ x, const float* __restrict__ state,
    const float* __restrict__ acc_ctx, const int* __restrict__ fix_pt,
    const float* __restrict__ ln1_g, const float* __restrict__ ln1_b,
    unsigned short* __restrict__ normed, float* __restrict__ ctx0,
    float* __restrict__ newacc)
{
    int bid = blockIdx.x;
    int t = threadIdx.x;
    if (bid >= MROWS) {
        ushort4 z = make_ushort4(0, 0, 0, 0);
        ((ushort4*)(normed + (size_t)bid * DIM))[t] = z;
        return;
    }
    int b = bid / LCTX;
    int r = bid - b * LCTX;
    const float* src;
    if (r == 0) {
        src = state + (size_t)b * DIM;
    } else if (r <= NACC) {
        src = acc_ctx + ((size_t)b * NACC + (r - 1)) * DIM;
    } else {
        int fp = fix_pt[b];
        int start = fp - WIN / 2;
        if (start < 0) start = 0;
        if (start > NSEQ - WIN) start = NSEQ - WIN;
        src = x + ((size_t)b * NSEQ + start + (r - 1 - NACC)) * DIM;
    }
    float4 v = ((const float4*)src)[t];
    float s = v.x + v.y + v.z + v.w;
    float ss = v.x * v.x + v.y * v.y + v.z * v.z + v.w * v.w;
#pragma unroll
    for (int o = 32; o > 0; o >>= 1) { s += __shfl_down(s, o); ss += __shfl_down(ss, o); }
    __shared__ float rs[4], rss[4];
    int wid = t >> 6, lane = t & 63;
    if (lane == 0) { rs[wid] = s; rss[wid] = ss; }
    __syncthreads();
    float sum = rs[0] + rs[1] + rs[2] + rs[3];
    float sq  = rss[0] + rss[1] + rss[2] + rss[3];
    float mean = sum * (1.0f / DIM);
    float var = sq * (1.0f / DIM) - mean * mean;
    float rstd = rsqrtf(var + 1e-5f);
    float4 g  = ((const float4*)ln1_g)[t];
    float4 be = ((const float4*)ln1_b)[t];
    ushort4 nb;
    nb.x = f2b((v.x - mean) * rstd * g.x + be.x);
    nb.y = f2b((v.y - mean) * rstd * g.y + be.y);
    nb.z = f2b((v.z - mean) * rstd * g.z + be.z);
    nb.w = f2b((v.w - mean) * rstd * g.w + be.w);
    ((ushort4*)(normed + (size_t)bid * DIM))[t] = nb;
    if (r == 0) {
        ((float4*)(ctx0 + (size_t)b * DIM))[t] = v;
    } else {
        ((float4*)(newacc + ((size_t)b * (LCTX - 1) + (r - 1)) * DIM))[t] = v;
    }
}

// ---------------------------------------------------------------------------
// Kernel 2: convert in_proj_w (3072x1024 f32) -> bf16
// ---------------------------------------------------------------------------
__global__ __launch_bounds__(256) void convert_w_kernel(
    const float* __restrict__ w, unsigned short* __restrict__ wb, int n4)
{
    int idx = blockIdx.x * 256 + threadIdx.x;
    if (idx >= n4) return;
    float4 v = ((const float4*)w)[idx];
    ushort4 o;
    o.x = f2b(v.x); o.y = f2b(v.y); o.z = f2b(v.z); o.w = f2b(v.w);
    ((ushort4*)wb)[idx] = o;
}

// ---------------------------------------------------------------------------
// Kernel 3: KV GEMM, 256x256 tile, BK=64, 8 waves, 8-phase schedule (m201-style)
// C[m,n] = sum_k A[m,k]*Bw[n,k] + bias[n]
// LDS: [dbuf][A/B][half][128*64] bf16 = 128 KiB, XOR-swizzled 16B slots
// ---------------------------------------------------------------------------
__device__ inline void stage_half(const unsigned short* __restrict__ g,
                                  unsigned short* l, int t)
{
    // slot s holds global element (row = s>>3, c8 = (s&7) ^ (row&7)); LDS linear.
    {
        int r = t >> 3, c8 = (t & 7) ^ (r & 7);
        __builtin_amdgcn_global_load_lds(
            (const __attribute__((address_space(1))) void*)(g + (size_t)r * 1024 + c8 * 8),
            (__attribute__((address_space(3))) void*)(l + (size_t)t * 8), 16, 0, 0);
    }
    {
        int t2 = t + 512;
        int r = t2 >> 3, c8 = (t2 & 7) ^ (r & 7);
        __builtin_amdgcn_global_load_lds(
            (const __attribute__((address_space(1))) void*)(g + (size_t)r * 1024 + c8 * 8),
            (__attribute__((address_space(3))) void*)(l + (size_t)t2 * 8), 16, 0, 0);
    }
}

__device__ inline bf16x8 ldsw(const unsigned short* h, int r, int c8)
{
    int slot = r * 8 + (c8 ^ (r & 7));
    return *(const bf16x8*)(h + slot * 8);
}

__global__ __launch_bounds__(512, 2) void kv_gemm8_kernel(
    const unsigned short* __restrict__ A,
    const unsigned short* __restrict__ Bw,
    const float* __restrict__ bias,
    unsigned short* __restrict__ C)
{
    __shared__ unsigned short sh[2][2][2][128 * 64];
    const int mt = blockIdx.x, nt = blockIdx.y;
    const int t = threadIdx.x;
    const int wid = t >> 6, lane = t & 63;
    const int wm = wid >> 2, wn = wid & 3;
    const int l15 = lane & 15, l16 = lane >> 4;
    const int rB = (wn & 1) * 64;
    const unsigned short* Abase = A + (size_t)mt * 256 * 1024;
    const unsigned short* Bbase = Bw + (size_t)nt * 256 * 1024;

    f32x4 acc[8][4] = {};
    bf16x8 a[4][2], b[4][2];

    // prologue: tile0 {A0,A1,B0,B1}, tile1 {B0,B1}  (12 loads)
    stage_half(Abase,                   &sh[0][0][0][0], t);
    stage_half(Abase + 128 * 1024,      &sh[0][0][1][0], t);
    stage_half(Bbase,                   &sh[0][1][0][0], t);
    stage_half(Bbase + 128 * 1024,      &sh[0][1][1][0], t);
    stage_half(Bbase + 64,              &sh[1][1][0][0], t);
    stage_half(Bbase + 128 * 1024 + 64, &sh[1][1][1][0], t);
    asm volatile("s_waitcnt vmcnt(4)" ::: "memory");
    __builtin_amdgcn_s_barrier();

    auto ktile = [&](int T, bool stA, bool stB, bool steady) {
        const int d = T & 1;
        const unsigned short* AH = &sh[d][0][wm][0];
        const unsigned short* BH = &sh[d][1][wn >> 1][0];
        const int kA = (T + 1) * 64;
        const int kB = (T + 2) * 64;

        // ---------- phase A: ds A(rows 0..63)+B(n0,n1); stage (T+1).A0 ----------
#pragma unroll
        for (int i = 0; i < 4; ++i) {
            a[i][0] = ldsw(AH, i * 16 + l15, l16);
            a[i][1] = ldsw(AH, i * 16 + l15, 4 + l16);
        }
#pragma unroll
        for (int j = 0; j < 2; ++j) {
            b[j][0] = ldsw(BH, rB + j * 16 + l15, l16);
            b[j][1] = ldsw(BH, rB + j * 16 + l15, 4 + l16);
        }
        if (stA) stage_half(Abase + kA, &sh[d ^ 1][0][0][0], t);
        __builtin_amdgcn_sched_barrier(0);
        __builtin_amdgcn_s_barrier();
        asm volatile("s_waitcnt lgkmcnt(0)" ::: "memory");
        __builtin_amdgcn_sched_barrier(0);
        __builtin_amdgcn_s_setprio(1);
#pragma unroll
        for (int i = 0; i < 4; ++i)
#pragma unroll
            for (int j = 0; j < 2; ++j) {
                acc[i][j] = __builtin_amdgcn_mfma_f32_16x16x32_bf16(a[i][0], b[j][0], acc[i][j], 0, 0, 0);
                acc[i][j] = __builtin_amdgcn_mfma_f32_16x16x32_bf16(a[i][1], b[j][1], acc[i][j], 0, 0, 0);
            }
        __builtin_amdgcn_s_setprio(0);
        __builtin_amdgcn_sched_barrier(0);
        __builtin_amdgcn_s_barrier();

        // ---------- phase B: ds B(n2,n3); stage (T+1).A1 ----------
#pragma unroll
        for (int j = 2; j < 4; ++j) {
            b[j][0] = ldsw(BH, rB + j * 16 + l15, l16);
            b[j][1] = ldsw(BH, rB + j * 16 + l15, 4 + l16);
        }
        if (stA) stage_half(Abase + 128 * 1024 + kA, &sh[d ^ 1][0][1][0], t);
        __builtin_amdgcn_sched_barrier(0);
        __builtin_amdgcn_s_barrier();
        asm volatile("s_waitcnt lgkmcnt(0)" ::: "memory");
        __builtin_amdgcn_sched_barrier(0);
        __builtin_amdgcn_s_setprio(1);
#pragma unroll
        for (int i = 0; i < 4; ++i)
#pragma unroll
            for (int j = 2; j < 4; ++j) {
                acc[i][j] = __builtin_amdgcn_mfma_f32_16x16x32_bf16(a[i][0], b[j][0], acc[i][j], 0, 0, 0);
                acc[i][j] = __builtin_amdgcn_mfma_f32_16x16x32_bf16(a[i][1], b[j][1], acc[i][j], 0, 0, 0);
            }
        __builtin_amdgcn_s_setprio(0);
        __builtin_amdgcn_sched_barrier(0);
        __builtin_amdgcn_s_barrier();

        // ---------- phase C: ds A(rows 64..127); stage (T+2).B0 ----------
#pragma unroll
        for (int i = 0; i < 4; ++i) {
            a[i][0] = ldsw(AH, 64 + i * 16 + l15, l16);
            a[i][1] = ldsw(AH, 64 + i * 16 + l15, 4 + l16);
        }
        if (stB) stage_half(Bbase + kB, &sh[d][1][0][0], t);
        __builtin_amdgcn_sched_barrier(0);
        __builtin_amdgcn_s_barrier();
        asm volatile("s_waitcnt lgkmcnt(0)" ::: "memory");
        __builtin_amdgcn_sched_barrier(0);
        __builtin_amdgcn_s_setprio(1);
#pragma unroll
        for (int i = 0; i < 4; ++i)
#pragma unroll
            for (int j = 0; j < 2; ++j) {
                acc[4 + i][j] = __builtin_amdgcn_mfma_f32_16x16x32_bf16(a[i][0], b[j][0], acc[4 + i][j], 0, 0, 0);
                acc[4 + i][j] = __builtin_amdgcn_mfma_f32_16x16x32_bf16(a[i][1], b[j][1], acc[4 + i][j], 0, 0, 0);
            }
        __builtin_amdgcn_s_setprio(0);
        __builtin_amdgcn_sched_barrier(0);
        __builtin_amdgcn_s_barrier();

        // ---------- phase D: no ds; stage (T+2).B1; counted vmcnt ----------
        if (stB) stage_half(Bbase + 128 * 1024 + kB, &sh[d][1][1][0], t);
        __builtin_amdgcn_sched_barrier(0);
        __builtin_amdgcn_s_barrier();
        asm volatile("s_waitcnt lgkmcnt(0)" ::: "memory");
        __builtin_amdgcn_sched_barrier(0);
        __builtin_amdgcn_s_setprio(1);
#pragma unroll
        for (int i = 0; i < 4; ++i)
#pragma unroll
            for (int j = 2; j < 4; ++j) {
                acc[4 + i][j] = __builtin_amdgcn_mfma_f32_16x16x32_bf16(a[i][0], b[j][0], acc[4 + i][j], 0, 0, 0);
                acc[4 + i][j] = __builtin_amdgcn_mfma_f32_16x16x32_bf16(a[i][1], b[j][1], acc[4 + i][j], 0, 0, 0);
            }
        __builtin_amdgcn_s_setprio(0);
        if (steady) {
            asm volatile("s_waitcnt vmcnt(4)" ::: "memory");
        } else {
            asm volatile("s_waitcnt vmcnt(0)" ::: "memory");
        }
        __builtin_amdgcn_sched_barrier(0);
        __builtin_amdgcn_s_barrier();
    };

    for (int T = 0; T < 14; ++T) ktile(T, true, true, true);
    ktile(14, true, false, false);
    ktile(15, false, false, false);

    // epilogue
#pragma unroll
    for (int i = 0; i < 8; ++i) {
        int gmb = mt * 256 + wm * 128 + i * 16 + l16 * 4;
#pragma unroll
        for (int j = 0; j < 4; ++j) {
            int gn = nt * 256 + wn * 64 + j * 16 + l15;
            float bs = bias[gn];
#pragma unroll
            for (int r = 0; r < 4; ++r) {
                int gm = gmb + r;
                if (gm < MROWS) C[(size_t)gm * NKV + gn] = f2b(acc[i][j][r] + bs);
            }
        }
    }
}

// ---------------------------------------------------------------------------
// Kernel 4: q0[b,d] = sum_k normed[b,0,k]*Wq[d,k] + bq[d]  (wave per output)
// ---------------------------------------------------------------------------
__global__ __launch_bounds__(256) void q_proj_kernel(
    const unsigned short* __restrict__ normed, const unsigned short* __restrict__ Wb,
    const float* __restrict__ bias, float* __restrict__ q0)
{
    int gw = blockIdx.x * 4 + (threadIdx.x >> 6);
    int lane = threadIdx.x & 63;
    int b = gw >> 10, d = gw & 1023;
    const unsigned short* nr = normed + (size_t)(b * LCTX) * DIM;
    const unsigned short* wr = Wb + (size_t)d * DIM;
    float s = 0.f;
#pragma unroll
    for (int kk = 0; kk < 16; ++kk) {
        int k = kk * 64 + lane;
        s += b2f(nr[k]) * b2f(wr[k]);
    }
#pragma unroll
    for (int o = 32; o > 0; o >>= 1) s += __shfl_down(s, o);
    if (lane == 0) q0[gw] = s + bias[d];
}

// ---------------------------------------------------------------------------
// Kernel 5: attention decode, one block per (b,h)
// ---------------------------------------------------------------------------
__global__ __launch_bounds__(256) void attn_kernel(
    const float* __restrict__ q0, const unsigned short* __restrict__ kv,
    float* __restrict__ o_all)
{
    int b = blockIdx.x >> 4, h = blockIdx.x & 15;
    int t = threadIdx.x;
    __shared__ float qs[64];
    __shared__ float sc[LCTX];
    __shared__ float red1[4], red2[4];
    __shared__ float po[4][64];
    if (t < 64) qs[t] = q0[b * 1024 + h * 64 + t];
    __syncthreads();
    float lmax = -1e30f;
    for (int l = t; l < LCTX; l += 256) {
        const unsigned short* kr = kv + ((size_t)(b * LCTX + l)) * NKV + h * 64;
        const uint4* k4 = (const uint4*)kr;
        float s = 0.f;
#pragma unroll
        for (int c = 0; c < 8; ++c) {
            uint4 u = k4[c];
            s += qs[c * 8 + 0] * b2f((unsigned short)(u.x & 0xffffu));
            s += qs[c * 8 + 1] * b2f((unsigned short)(u.x >> 16));
            s += qs[c * 8 + 2] * b2f((unsigned short)(u.y & 0xffffu));
            s += qs[c * 8 + 3] * b2f((unsigned short)(u.y >> 16));
            s += qs[c * 8 + 4] * b2f((unsigned short)(u.z & 0xffffu));
            s += qs[c * 8 + 5] * b2f((unsigned short)(u.z >> 16));
            s += qs[c * 8 + 6] * b2f((unsigned short)(u.w & 0xffffu));
            s += qs[c * 8 + 7] * b2f((unsigned short)(u.w >> 16));
        }
        s *= 0.125f;
        sc[l] = s;
        lmax = fmaxf(lmax, s);
    }
#pragma unroll
    for (int o = 32; o > 0; o >>= 1) lmax = fmaxf(lmax, __shfl_down(lmax, o));
    int wid = t >> 6, lane = t & 63;
    if (lane == 0) red1[wid] = lmax;
    __syncthreads();
    float m = fmaxf(fmaxf(red1[0], red1[1]), fmaxf(red1[2], red1[3]));
    float lsum = 0.f;
    for (int l = t; l < LCTX; l += 256) {
        float p = __expf(sc[l] - m);
        sc[l] = p;
        lsum += p;
    }
#pragma unroll
    for (int o = 32; o > 0; o >>= 1) lsum += __shfl_down(lsum, o);
    if (lane == 0) red2[wid] = lsum;
    __syncthreads();
    float S = red2[0] + red2[1] + red2[2] + red2[3];
    int d = t & 63, ls = t >> 6;
    float a = 0.f;
    for (int l = ls; l < LCTX; l += 4) {
        const unsigned short* vr = kv + ((size_t)(b * LCTX + l)) * NKV + 1024 + h * 64;
        a += sc[l] * b2f(vr[d]);
    }
    po[ls][d] = a;
    __syncthreads();
    if (t < 64) {
        float o = (po[0][t] + po[1][t] + po[2][t] + po[3][t]) / S;
        o_all[b * 1024 + h * 64 + t] = o;
    }
}

// ---------------------------------------------------------------------------
// Kernel 6: cls_pre[b,i] = ctx0[b,i] + sum_j o_all[b,j]*out_w[i,j] + out_b[i]
// ---------------------------------------------------------------------------
__global__ __launch_bounds__(256) void out_proj_kernel(
    const float* __restrict__ o_all, const float* __restrict__ out_w,
    const float* __restrict__ out_b, const float* __restrict__ ctx0,
    float* __restrict__ cls_pre)
{
    int gw = blockIdx.x * 4 + (threadIdx.x >> 6);
    int lane = threadIdx.x & 63;
    int b = gw >> 10, i = gw & 1023;
    const float* orow = o_all + (size_t)b * 1024;
    const float* wrow = out_w + (size_t)i * 1024;
    float s = 0.f;
#pragma unroll
    for (int kk = 0; kk < 16; ++kk) {
        int k = kk * 64 + lane;
        s += orow[k] * wrow[k];
    }
#pragma unroll
    for (int o = 32; o > 0; o >>= 1) s += __shfl_down(s, o);
    if (lane == 0) cls_pre[gw] = ctx0[gw] + s + out_b[i];
}

// ---------------------------------------------------------------------------
// Kernel 7: LN2 over cls_pre rows
// ---------------------------------------------------------------------------
__global__ __launch_bounds__(256) void ln2_kernel(
    const float* __restrict__ cls_pre, const float* __restrict__ g,
    const float* __restrict__ be, float* __restrict__ ln2o)
{
    int b = blockIdx.x, t = threadIdx.x;
    float4 v = ((const float4*)(cls_pre + (size_t)b * DIM))[t];
    float s = v.x + v.y + v.z + v.w;
    float ss = v.x * v.x + v.y * v.y + v.z * v.z + v.w * v.w;
#pragma unroll
    for (int o = 32; o > 0; o >>= 1) { s += __shfl_down(s, o); ss += __shfl_down(ss, o); }
    __shared__ float rs[4], rss[4];
    int wid = t >> 6, lane = t & 63;
    if (lane == 0) { rs[wid] = s; rss[wid] = ss; }
    __syncthreads();
    float sum = rs[0] + rs[1] + rs[2] + rs[3];
    float sq  = rss[0] + rss[1] + rss[2] + rss[3];
    float mean = sum * (1.0f / DIM);
    float var = sq * (1.0f / DIM) - mean * mean;
    float rstd = rsqrtf(var + 1e-5f);
    float4 gv = ((const float4*)g)[t];
    float4 bv = ((const float4*)be)[t];
    float4 o;
    o.x = (v.x - mean) * rstd * gv.x + bv.x;
    o.y = (v.y - mean) * rstd * gv.y + bv.y;
    o.z = (v.z - mean) * rstd * gv.z + bv.z;
    o.w = (v.w - mean) * rstd * gv.w + bv.w;
    ((float4*)(ln2o + (size_t)b * DIM))[t] = o;
}

// ---------------------------------------------------------------------------
// Kernel 8: h = gelu(ln2 @ w1 + b1)
// ---------------------------------------------------------------------------
__global__ __launch_bounds__(256) void mlp1_kernel(
    const float* __restrict__ ln2v, const float* __restrict__ w1,
    const float* __restrict__ b1, float* __restrict__ h)
{
    __shared__ float l2s[8][1024];
    __shared__ float part[8][32][8];
    int jc = blockIdx.x;   // 0..127
    int bh = blockIdx.y;   // 0..1
    int t = threadIdx.x;
    const float4* src = (const float4*)(ln2v + (size_t)bh * 8 * 1024);
#pragma unroll
    for (int i = 0; i < 8; ++i)
        ((float4*)&l2s[0][0])[i * 256 + t] = src[i * 256 + t];
    __syncthreads();
    int jl = t & 31, ks = t >> 5;
    int j = jc * 32 + jl;
    float acc[8] = {};
    for (int kk = 0; kk < 128; ++kk) {
        int k = ks * 128 + kk;
        float wv = w1[(size_t)k * 4096 + j];
#pragma unroll
        for (int bb = 0; bb < 8; ++bb) acc[bb] += l2s[bb][k] * wv;
    }
#pragma unroll
    for (int bb = 0; bb < 8; ++bb) part[ks][jl][bb] = acc[bb];
    __syncthreads();
    int jl2 = t >> 3, bb = t & 7;
    float s = 0.f;
#pragma unroll
    for (int q = 0; q < 8; ++q) s += part[q][jl2][bb];
    int jj = jc * 32 + jl2;
    s += b1[jj];
    float ge = 0.5f * s * (1.0f + erff(s * 0.70710678118f));
    h[(size_t)(bh * 8 + bb) * 4096 + jj] = ge;
}

// ---------------------------------------------------------------------------
// Kernel 9: cls_out = cls_pre + h @ w2 + b2
// ---------------------------------------------------------------------------
__global__ __launch_bounds__(256) void mlp2_kernel(
    const float* __restrict__ h, const float* __restrict__ w2,
    const float* __restrict__ b2, const float* __restrict__ cls_pre,
    float* __restrict__ outp)
{
    __shared__ float hs[2][4096];
    __shared__ float part[8][32][2];
    int ic = blockIdx.x;  // 0..31
    int bq = blockIdx.y;  // 0..7
    int t = threadIdx.x;
    const float4* src = (const float4*)(h + (size_t)bq * 2 * 4096);
#pragma unroll
    for (int i = 0; i < 8; ++i)
        ((float4*)&hs[0][0])[i * 256 + t] = src[i * 256 + t];
    __syncthreads();
    int jl = t & 31, ks = t >> 5;
    int i = ic * 32 + jl;
    float a0 = 0.f, a1 = 0.f;
    for (int kk = 0; kk < 512; ++kk) {
        int k = ks * 512 + kk;
        float wv = w2[(size_t)k * 1024 + i];
        a0 += hs[0][k] * wv;
        a1 += hs[1][k] * wv;
    }
    part[ks][jl][0] = a0;
    part[ks][jl][1] = a1;
    __syncthreads();
    if (t < 64) {
        int jl2 = t >> 1, bb = t & 1;
        float s = 0.f;
#pragma unroll
        for (int q = 0; q < 8; ++q) s += part[q][jl2][bb];
        int ii = ic * 32 + jl2;
        int bbb = bq * 2 + bb;
        outp[(size_t)bbb * 1024 + ii] = cls_pre[(size_t)bbb * 1024 + ii] + s + b2[ii];
    }
}

// ---------------------------------------------------------------------------
extern "C" void kernel_launch(void* const* d_in, const int* in_sizes, int n_in,
                              void* d_out, int out_size, void* d_ws, size_t ws_size,
                              hipStream_t stream)
{
    const float* x        = (const float*)d_in[0];
    const float* state    = (const float*)d_in[1];
    const float* acc_ctx  = (const float*)d_in[2];
    const int*   fix_pt   = (const int*)d_in[3];
    const float* in_proj_w = (const float*)d_in[4];
    const float* in_proj_b = (const float*)d_in[5];
    const float* out_w    = (const float*)d_in[6];
    const float* out_b    = (const float*)d_in[7];
    const float* ln1_g    = (const float*)d_in[8];
    const float* ln1_b    = (const float*)d_in[9];
    const float* ln2_g    = (const float*)d_in[10];
    const float* ln2_b    = (const float*)d_in[11];
    const float* w1       = (const float*)d_in[12];
    const float* b1       = (const float*)d_in[13];
    const float* w2       = (const float*)d_in[14];
    const float* b2       = (const float*)d_in[15];
    float* outp = (float*)d_out;

    char* ws = (char*)d_ws;
    unsigned short* normed = (unsigned short*)ws; ws += (size_t)MPAD2 * DIM * 2;
    unsigned short* Wb     = (unsigned short*)ws; ws += (size_t)3072 * DIM * 2;
    unsigned short* kvb    = (unsigned short*)ws; ws += (size_t)MROWS * NKV * 2;
    float* ctx0    = (float*)ws; ws += (size_t)NB * DIM * 4;
    float* q0      = (float*)ws; ws += (size_t)NB * DIM * 4;
    float* o_all   = (float*)ws; ws += (size_t)NB * DIM * 4;
    float* cls_pre = (float*)ws; ws += (size_t)NB * DIM * 4;
    float* ln2v    = (float*)ws; ws += (size_t)NB * DIM * 4;
    float* hbuf    = (float*)ws; ws += (size_t)NB * 4096 * 4;

    float* newacc = outp + (size_t)NB * DIM;

    hipLaunchKernelGGL(build_ln_kernel, dim3(MPAD2), dim3(256), 0, stream,
                       x, state, acc_ctx, fix_pt, ln1_g, ln1_b, normed, ctx0, newacc);
    hipLaunchKernelGGL(convert_w_kernel, dim3(3072), dim3(256), 0, stream,
                       in_proj_w, Wb, 3072 * DIM / 4);
    hipLaunchKernelGGL(kv_gemm8_kernel, dim3(49, 8), dim3(512), 0, stream,
                       normed, Wb + (size_t)1024 * DIM, in_proj_b + 1024, kvb);
    hipLaunchKernelGGL(q_proj_kernel, dim3(4096), dim3(256), 0, stream,
                       normed, Wb, in_proj_b, q0);
    hipLaunchKernelGGL(attn_kernel, dim3(256), dim3(256), 0, stream,
                       q0, kvb, o_all);
    hipLaunchKernelGGL(out_proj_kernel, dim3(4096), dim3(256), 0, stream,
                       o_all, out_w, out_b, ctx0, cls_pre);
    hipLaunchKernelGGL(ln2_kernel, dim3(16), dim3(256), 0, stream,
                       cls_pre, ln2_g, ln2_b, ln2v);
    hipLaunchKernelGGL(mlp1_kernel, dim3(128, 2), dim3(256), 0, stream,
                       ln2v, w1, b1, hbuf);
    hipLaunchKernelGGL(mlp2_kernel, dim3(32, 8), dim3(256), 0, stream,
                       hbuf, w2, b2, cls_pre, outp);
}

// Round 3
// 221.219 us; speedup vs baseline: 1.1353x; 1.0558x over previous
//
#include <hip/hip_runtime.h>
#include <hip/hip_bf16.h>
#include <math.h>

#define DIM 1024
#define NHEADS 16
#define HD 64
#define WIN 256
#define NB 16
#define NSEQ 4096
#define NACC 512
#define LCTX 769      // 1 + 512 + 256
#define MROWS 12304   // 16*769
#define MPAD2 12544   // 49*256
#define NKV 2048

typedef short bf16x8 __attribute__((ext_vector_type(8)));
typedef float f32x4 __attribute__((ext_vector_type(4)));

__device__ inline unsigned short f2b(float f) {
    union { float f; unsigned int u; } c; c.f = f;
    unsigned int u = c.u;
    u += 0x7FFFu + ((u >> 16) & 1u);
    return (unsigned short)(u >> 16);
}
__device__ inline float b2f(unsigned short h) {
    union { unsigned int u; float f; } c; c.u = ((unsigned int)h) << 16;
    return c.f;
}

// ---------------------------------------------------------------------------
// Kernel 1: build ctx rows, LN1 -> normed (bf16), write new_acc, save ctx row 0
// ---------------------------------------------------------------------------
__global__ __launch_bounds__(256) void build_ln_kernel(
    const float* __restrict__ x, const float* __restrict__ state,
    const float* __restrict__ acc_ctx, const int* __restrict__ fix_pt,
    const float* __restrict__ ln1_g, const float* __restrict__ ln1_b,
    unsigned short* __restrict__ normed, float* __restrict__ ctx0,
    float* __restrict__ newacc)
{
    int bid = blockIdx.x;
    int t = threadIdx.x;
    if (bid >= MROWS) {
        ushort4 z = make_ushort4(0, 0, 0, 0);
        ((ushort4*)(normed + (size_t)bid * DIM))[t] = z;
        return;
    }
    int b = bid / LCTX;
    int r = bid - b * LCTX;
    const float* src;
    if (r == 0) {
        src = state + (size_t)b * DIM;
    } else if (r <= NACC) {
        src = acc_ctx + ((size_t)b * NACC + (r - 1)) * DIM;
    } else {
        int fp = fix_pt[b];
        int start = fp - WIN / 2;
        if (start < 0) start = 0;
        if (start > NSEQ - WIN) start = NSEQ - WIN;
        src = x + ((size_t)b * NSEQ + start + (r - 1 - NACC)) * DIM;
    }
    float4 v = ((const float4*)src)[t];
    float s = v.x + v.y + v.z + v.w;
    float ss = v.x * v.x + v.y * v.y + v.z * v.z + v.w * v.w;
#pragma unroll
    for (int o = 32; o > 0; o >>= 1) { s += __shfl_down(s, o); ss += __shfl_down(ss, o); }
    __shared__ float rs[4], rss[4];
    int wid = t >> 6, lane = t & 63;
    if (lane == 0) { rs[wid] = s; rss[wid] = ss; }
    __syncthreads();
    float sum = rs[0] + rs[1] + rs[2] + rs[3];
    float sq  = rss[0] + rss[1] + rss[2] + rss[3];
    float mean = sum * (1.0f / DIM);
    float var = sq * (1.0f / DIM) - mean * mean;
    float rstd = rsqrtf(var + 1e-5f);
    float4 g  = ((const float4*)ln1_g)[t];
    float4 be = ((const float4*)ln1_b)[t];
    ushort4 nb;
    nb.x = f2b((v.x - mean) * rstd * g.x + be.x);
    nb.y = f2b((v.y - mean) * rstd * g.y + be.y);
    nb.z = f2b((v.z - mean) * rstd * g.z + be.z);
    nb.w = f2b((v.w - mean) * rstd * g.w + be.w);
    ((ushort4*)(normed + (size_t)bid * DIM))[t] = nb;
    if (r == 0) {
        ((float4*)(ctx0 + (size_t)b * DIM))[t] = v;
    } else {
        ((float4*)(newacc + ((size_t)b * (LCTX - 1) + (r - 1)) * DIM))[t] = v;
    }
}

// ---------------------------------------------------------------------------
// Kernel 2: convert in_proj_w (3072x1024 f32) -> bf16
// ---------------------------------------------------------------------------
__global__ __launch_bounds__(256) void convert_w_kernel(
    const float* __restrict__ w, unsigned short* __restrict__ wb, int n4)
{
    int idx = blockIdx.x * 256 + threadIdx.x;
    if (idx >= n4) return;
    float4 v = ((const float4*)w)[idx];
    ushort4 o;
    o.x = f2b(v.x); o.y = f2b(v.y); o.z = f2b(v.z); o.w = f2b(v.w);
    ((ushort4*)wb)[idx] = o;
}

// ---------------------------------------------------------------------------
// Kernel 3: KV GEMM, 256x256 tile, BK=64, 8 waves, 8-phase schedule
// ---------------------------------------------------------------------------
__device__ inline void stage_half(const unsigned short* __restrict__ g,
                                  unsigned short* l, int t)
{
    {
        int r = t >> 3, c8 = (t & 7) ^ (r & 7);
        __builtin_amdgcn_global_load_lds(
            (const __attribute__((address_space(1))) void*)(g + (size_t)r * 1024 + c8 * 8),
            (__attribute__((address_space(3))) void*)(l + (size_t)t * 8), 16, 0, 0);
    }
    {
        int t2 = t + 512;
        int r = t2 >> 3, c8 = (t2 & 7) ^ (r & 7);
        __builtin_amdgcn_global_load_lds(
            (const __attribute__((address_space(1))) void*)(g + (size_t)r * 1024 + c8 * 8),
            (__attribute__((address_space(3))) void*)(l + (size_t)t2 * 8), 16, 0, 0);
    }
}

__device__ inline bf16x8 ldsw(const unsigned short* h, int r, int c8)
{
    int slot = r * 8 + (c8 ^ (r & 7));
    return *(const bf16x8*)(h + slot * 8);
}

__global__ __launch_bounds__(512, 2) void kv_gemm8_kernel(
    const unsigned short* __restrict__ A,
    const unsigned short* __restrict__ Bw,
    const float* __restrict__ bias,
    unsigned short* __restrict__ C)
{
    __shared__ unsigned short sh[2][2][2][128 * 64];
    const int mt = blockIdx.x, nt = blockIdx.y;
    const int t = threadIdx.x;
    const int wid = t >> 6, lane = t & 63;
    const int wm = wid >> 2, wn = wid & 3;
    const int l15 = lane & 15, l16 = lane >> 4;
    const int rB = (wn & 1) * 64;
    const unsigned short* Abase = A + (size_t)mt * 256 * 1024;
    const unsigned short* Bbase = Bw + (size_t)nt * 256 * 1024;

    f32x4 acc[8][4] = {};
    bf16x8 a[4][2], b[4][2];

    stage_half(Abase,                   &sh[0][0][0][0], t);
    stage_half(Abase + 128 * 1024,      &sh[0][0][1][0], t);
    stage_half(Bbase,                   &sh[0][1][0][0], t);
    stage_half(Bbase + 128 * 1024,      &sh[0][1][1][0], t);
    stage_half(Bbase + 64,              &sh[1][1][0][0], t);
    stage_half(Bbase + 128 * 1024 + 64, &sh[1][1][1][0], t);
    asm volatile("s_waitcnt vmcnt(4)" ::: "memory");
    __builtin_amdgcn_s_barrier();

    auto ktile = [&](int T, bool stA, bool stB, bool steady) {
        const int d = T & 1;
        const unsigned short* AH = &sh[d][0][wm][0];
        const unsigned short* BH = &sh[d][1][wn >> 1][0];
        const int kA = (T + 1) * 64;
        const int kB = (T + 2) * 64;

#pragma unroll
        for (int i = 0; i < 4; ++i) {
            a[i][0] = ldsw(AH, i * 16 + l15, l16);
            a[i][1] = ldsw(AH, i * 16 + l15, 4 + l16);
        }
#pragma unroll
        for (int j = 0; j < 2; ++j) {
            b[j][0] = ldsw(BH, rB + j * 16 + l15, l16);
            b[j][1] = ldsw(BH, rB + j * 16 + l15, 4 + l16);
        }
        if (stA) stage_half(Abase + kA, &sh[d ^ 1][0][0][0], t);
        __builtin_amdgcn_sched_barrier(0);
        __builtin_amdgcn_s_barrier();
        asm volatile("s_waitcnt lgkmcnt(0)" ::: "memory");
        __builtin_amdgcn_sched_barrier(0);
        __builtin_amdgcn_s_setprio(1);
#pragma unroll
        for (int i = 0; i < 4; ++i)
#pragma unroll
            for (int j = 0; j < 2; ++j) {
                acc[i][j] = __builtin_amdgcn_mfma_f32_16x16x32_bf16(a[i][0], b[j][0], acc[i][j], 0, 0, 0);
                acc[i][j] = __builtin_amdgcn_mfma_f32_16x16x32_bf16(a[i][1], b[j][1], acc[i][j], 0, 0, 0);
            }
        __builtin_amdgcn_s_setprio(0);
        __builtin_amdgcn_sched_barrier(0);
        __builtin_amdgcn_s_barrier();

#pragma unroll
        for (int j = 2; j < 4; ++j) {
            b[j][0] = ldsw(BH, rB + j * 16 + l15, l16);
            b[j][1] = ldsw(BH, rB + j * 16 + l15, 4 + l16);
        }
        if (stA) stage_half(Abase + 128 * 1024 + kA, &sh[d ^ 1][0][1][0], t);
        __builtin_amdgcn_sched_barrier(0);
        __builtin_amdgcn_s_barrier();
        asm volatile("s_waitcnt lgkmcnt(0)" ::: "memory");
        __builtin_amdgcn_sched_barrier(0);
        __builtin_amdgcn_s_setprio(1);
#pragma unroll
        for (int i = 0; i < 4; ++i)
#pragma unroll
            for (int j = 2; j < 4; ++j) {
                acc[i][j] = __builtin_amdgcn_mfma_f32_16x16x32_bf16(a[i][0], b[j][0], acc[i][j], 0, 0, 0);
                acc[i][j] = __builtin_amdgcn_mfma_f32_16x16x32_bf16(a[i][1], b[j][1], acc[i][j], 0, 0, 0);
            }
        __builtin_amdgcn_s_setprio(0);
        __builtin_amdgcn_sched_barrier(0);
        __builtin_amdgcn_s_barrier();

#pragma unroll
        for (int i = 0; i < 4; ++i) {
            a[i][0] = ldsw(AH, 64 + i * 16 + l15, l16);
            a[i][1] = ldsw(AH, 64 + i * 16 + l15, 4 + l16);
        }
        if (stB) stage_half(Bbase + kB, &sh[d][1][0][0], t);
        __builtin_amdgcn_sched_barrier(0);
        __builtin_amdgcn_s_barrier();
        asm volatile("s_waitcnt lgkmcnt(0)" ::: "memory");
        __builtin_amdgcn_sched_barrier(0);
        __builtin_amdgcn_s_setprio(1);
#pragma unroll
        for (int i = 0; i < 4; ++i)
#pragma unroll
            for (int j = 0; j < 2; ++j) {
                acc[4 + i][j] = __builtin_amdgcn_mfma_f32_16x16x32_bf16(a[i][0], b[j][0], acc[4 + i][j], 0, 0, 0);
                acc[4 + i][j] = __builtin_amdgcn_mfma_f32_16x16x32_bf16(a[i][1], b[j][1], acc[4 + i][j], 0, 0, 0);
            }
        __builtin_amdgcn_s_setprio(0);
        __builtin_amdgcn_sched_barrier(0);
        __builtin_amdgcn_s_barrier();

        if (stB) stage_half(Bbase + 128 * 1024 + kB, &sh[d][1][1][0], t);
        __builtin_amdgcn_sched_barrier(0);
        __builtin_amdgcn_s_barrier();
        asm volatile("s_waitcnt lgkmcnt(0)" ::: "memory");
        __builtin_amdgcn_sched_barrier(0);
        __builtin_amdgcn_s_setprio(1);
#pragma unroll
        for (int i = 0; i < 4; ++i)
#pragma unroll
            for (int j = 2; j < 4; ++j) {
                acc[4 + i][j] = __builtin_amdgcn_mfma_f32_16x16x32_bf16(a[i][0], b[j][0], acc[4 + i][j], 0, 0, 0);
                acc[4 + i][j] = __builtin_amdgcn_mfma_f32_16x16x32_bf16(a[i][1], b[j][1], acc[4 + i][j], 0, 0, 0);
            }
        __builtin_amdgcn_s_setprio(0);
        if (steady) {
            asm volatile("s_waitcnt vmcnt(4)" ::: "memory");
        } else {
            asm volatile("s_waitcnt vmcnt(0)" ::: "memory");
        }
        __builtin_amdgcn_sched_barrier(0);
        __builtin_amdgcn_s_barrier();
    };

    for (int T = 0; T < 14; ++T) ktile(T, true, true, true);
    ktile(14, true, false, false);
    ktile(15, false, false, false);

#pragma unroll
    for (int i = 0; i < 8; ++i) {
        int gmb = mt * 256 + wm * 128 + i * 16 + l16 * 4;
#pragma unroll
        for (int j = 0; j < 4; ++j) {
            int gn = nt * 256 + wn * 64 + j * 16 + l15;
            float bs = bias[gn];
#pragma unroll
            for (int r = 0; r < 4; ++r) {
                int gm = gmb + r;
                if (gm < MROWS) C[(size_t)gm * NKV + gn] = f2b(acc[i][j][r] + bs);
            }
        }
    }
}

// ---------------------------------------------------------------------------
// Kernel 4: attention decode with fused q-projection, one block per (b,h)
// ---------------------------------------------------------------------------
__global__ __launch_bounds__(256) void attn_kernel(
    const unsigned short* __restrict__ normed,
    const unsigned short* __restrict__ Wq, const float* __restrict__ bq,
    const unsigned short* __restrict__ kv, float* __restrict__ o_all)
{
    int b = blockIdx.x >> 4, h = blockIdx.x & 15;
    int t = threadIdx.x;
    int wave = t >> 6, lane = t & 63;
    __shared__ float qs[64];
    __shared__ float sc[LCTX];
    __shared__ float red1[4], red2[4];
    __shared__ float po[4][64];

    // --- fused q projection: qs[d] = normed[b,0,:] . Wq[h*64+d,:] + bq ---
    {
        const unsigned short* nr = normed + (size_t)(b * LCTX) * DIM;
        bf16x8 n0 = *(const bf16x8*)(nr + lane * 16);
        bf16x8 n1 = *(const bf16x8*)(nr + lane * 16 + 8);
#pragma unroll
        for (int jj = 0; jj < 16; ++jj) {
            int d = wave * 16 + jj;
            const unsigned short* wr = Wq + (size_t)(h * 64 + d) * DIM;
            bf16x8 w0 = *(const bf16x8*)(wr + lane * 16);
            bf16x8 w1 = *(const bf16x8*)(wr + lane * 16 + 8);
            float s = 0.f;
#pragma unroll
            for (int u = 0; u < 8; ++u)
                s += b2f((unsigned short)n0[u]) * b2f((unsigned short)w0[u]);
#pragma unroll
            for (int u = 0; u < 8; ++u)
                s += b2f((unsigned short)n1[u]) * b2f((unsigned short)w1[u]);
#pragma unroll
            for (int o = 32; o > 0; o >>= 1) s += __shfl_down(s, o);
            if (lane == 0) qs[d] = s + bq[h * 64 + d];
        }
    }
    __syncthreads();

    float lmax = -1e30f;
    for (int l = t; l < LCTX; l += 256) {
        const unsigned short* kr = kv + ((size_t)(b * LCTX + l)) * NKV + h * 64;
        const uint4* k4 = (const uint4*)kr;
        float s = 0.f;
#pragma unroll
        for (int c = 0; c < 8; ++c) {
            uint4 u = k4[c];
            s += qs[c * 8 + 0] * b2f((unsigned short)(u.x & 0xffffu));
            s += qs[c * 8 + 1] * b2f((unsigned short)(u.x >> 16));
            s += qs[c * 8 + 2] * b2f((unsigned short)(u.y & 0xffffu));
            s += qs[c * 8 + 3] * b2f((unsigned short)(u.y >> 16));
            s += qs[c * 8 + 4] * b2f((unsigned short)(u.z & 0xffffu));
            s += qs[c * 8 + 5] * b2f((unsigned short)(u.z >> 16));
            s += qs[c * 8 + 6] * b2f((unsigned short)(u.w & 0xffffu));
            s += qs[c * 8 + 7] * b2f((unsigned short)(u.w >> 16));
        }
        s *= 0.125f;
        sc[l] = s;
        lmax = fmaxf(lmax, s);
    }
#pragma unroll
    for (int o = 32; o > 0; o >>= 1) lmax = fmaxf(lmax, __shfl_down(lmax, o));
    if (lane == 0) red1[wave] = lmax;
    __syncthreads();
    float m = fmaxf(fmaxf(red1[0], red1[1]), fmaxf(red1[2], red1[3]));
    float lsum = 0.f;
    for (int l = t; l < LCTX; l += 256) {
        float p = __expf(sc[l] - m);
        sc[l] = p;
        lsum += p;
    }
#pragma unroll
    for (int o = 32; o > 0; o >>= 1) lsum += __shfl_down(lsum, o);
    if (lane == 0) red2[wave] = lsum;
    __syncthreads();
    float S = red2[0] + red2[1] + red2[2] + red2[3];
    int d = t & 63, ls = t >> 6;
    float a = 0.f;
    for (int l = ls; l < LCTX; l += 4) {
        const unsigned short* vr = kv + ((size_t)(b * LCTX + l)) * NKV + 1024 + h * 64;
        a += sc[l] * b2f(vr[d]);
    }
    po[ls][d] = a;
    __syncthreads();
    if (t < 64) {
        float o = (po[0][t] + po[1][t] + po[2][t] + po[3][t]) / S;
        o_all[b * 1024 + h * 64 + t] = o;
    }
}

// ---------------------------------------------------------------------------
// Kernel 5: cls_pre[b,i] = ctx0[b,i] + sum_j o_all[b,j]*out_w[i,j] + out_b[i]
// ---------------------------------------------------------------------------
__global__ __launch_bounds__(256) void out_proj_kernel(
    const float* __restrict__ o_all, const float* __restrict__ out_w,
    const float* __restrict__ out_b, const float* __restrict__ ctx0,
    float* __restrict__ cls_pre)
{
    int gw = blockIdx.x * 4 + (threadIdx.x >> 6);
    int lane = threadIdx.x & 63;
    int b = gw >> 10, i = gw & 1023;
    const float* orow = o_all + (size_t)b * 1024;
    const float* wrow = out_w + (size_t)i * 1024;
    float s = 0.f;
#pragma unroll
    for (int kk = 0; kk < 16; ++kk) {
        int k = kk * 64 + lane;
        s += orow[k] * wrow[k];
    }
#pragma unroll
    for (int o = 32; o > 0; o >>= 1) s += __shfl_down(s, o);
    if (lane == 0) cls_pre[gw] = ctx0[gw] + s + out_b[i];
}

// ---------------------------------------------------------------------------
// Kernel 6: LN2 over cls_pre rows; also init outp = cls_pre + b2
// ---------------------------------------------------------------------------
__global__ __launch_bounds__(256) void ln2_kernel(
    const float* __restrict__ cls_pre, const float* __restrict__ g,
    const float* __restrict__ be, const float* __restrict__ b2,
    float* __restrict__ ln2o, float* __restrict__ outp)
{
    int b = blockIdx.x, t = threadIdx.x;
    float4 v = ((const float4*)(cls_pre + (size_t)b * DIM))[t];
    float s = v.x + v.y + v.z + v.w;
    float ss = v.x * v.x + v.y * v.y + v.z * v.z + v.w * v.w;
#pragma unroll
    for (int o = 32; o > 0; o >>= 1) { s += __shfl_down(s, o); ss += __shfl_down(ss, o); }
    __shared__ float rs[4], rss[4];
    int wid = t >> 6, lane = t & 63;
    if (lane == 0) { rs[wid] = s; rss[wid] = ss; }
    __syncthreads();
    float sum = rs[0] + rs[1] + rs[2] + rs[3];
    float sq  = rss[0] + rss[1] + rss[2] + rss[3];
    float mean = sum * (1.0f / DIM);
    float var = sq * (1.0f / DIM) - mean * mean;
    float rstd = rsqrtf(var + 1e-5f);
    float4 gv = ((const float4*)g)[t];
    float4 bv = ((const float4*)be)[t];
    float4 o;
    o.x = (v.x - mean) * rstd * gv.x + bv.x;
    o.y = (v.y - mean) * rstd * gv.y + bv.y;
    o.z = (v.z - mean) * rstd * gv.z + bv.z;
    o.w = (v.w - mean) * rstd * gv.w + bv.w;
    ((float4*)(ln2o + (size_t)b * DIM))[t] = o;
    float4 b2v = ((const float4*)b2)[t];
    float4 oi;
    oi.x = v.x + b2v.x; oi.y = v.y + b2v.y; oi.z = v.z + b2v.z; oi.w = v.w + b2v.w;
    ((float4*)(outp + (size_t)b * DIM))[t] = oi;
}

// ---------------------------------------------------------------------------
// Kernel 7: mlp1 partials: part[kq][b][j] = sum_{k in kq-range} ln2[b,k]*w1[k,j]
// grid (64 jc, 4 kq) x 256 thr; w1 read once, 256B-coalesced
// ---------------------------------------------------------------------------
__global__ __launch_bounds__(256) void mlp1p_kernel(
    const float* __restrict__ ln2v, const float* __restrict__ w1,
    float* __restrict__ part)
{
    __shared__ float l2s[16][256];
    __shared__ float red[4][64][16];
    int jc = blockIdx.x, kq = blockIdx.y;
    int t = threadIdx.x;
#pragma unroll
    for (int b = 0; b < 16; ++b)
        l2s[b][t] = ln2v[(size_t)b * 1024 + kq * 256 + t];
    __syncthreads();
    int jl = t & 63, ks = t >> 6;
    int j = jc * 64 + jl;
    float acc[16] = {};
    for (int kk = 0; kk < 64; ++kk) {
        int kl = ks * 64 + kk;
        float wv = w1[(size_t)(kq * 256 + kl) * 4096 + j];
#pragma unroll
        for (int b = 0; b < 16; ++b) acc[b] += l2s[b][kl] * wv;
    }
#pragma unroll
    for (int b = 0; b < 16; ++b) red[ks][jl][b] = acc[b];
    __syncthreads();
    int jl2 = t & 63, bq = t >> 6;
#pragma unroll
    for (int bb = 0; bb < 4; ++bb) {
        int b = bq * 4 + bb;
        float s = red[0][jl2][b] + red[1][jl2][b] + red[2][jl2][b] + red[3][jl2][b];
        part[((size_t)kq * 16 + b) * 4096 + jc * 64 + jl2] = s;
    }
}

// ---------------------------------------------------------------------------
// Kernel 8: mlp2 with in-LDS reduce+gelu of mlp1 partials, atomicAdd to outp
// grid (16 ic, 16 kq) x 256 thr; w2 read once, 256B-coalesced
// ---------------------------------------------------------------------------
__global__ __launch_bounds__(256) void mlp2a_kernel(
    const float* __restrict__ part, const float* __restrict__ b1,
    const float* __restrict__ w2, float* __restrict__ outp)
{
    __shared__ float hseg[16][256];
    __shared__ float red[4][64][16];
    int ic = blockIdx.x, kq = blockIdx.y;
    int t = threadIdx.x;
    // reconstruct h[b, kq*256 + t] for all b
    {
        int j = kq * 256 + t;
        float bb1 = b1[j];
#pragma unroll
        for (int b = 0; b < 16; ++b) {
            float s = part[((size_t)0 * 16 + b) * 4096 + j]
                    + part[((size_t)1 * 16 + b) * 4096 + j]
                    + part[((size_t)2 * 16 + b) * 4096 + j]
                    + part[((size_t)3 * 16 + b) * 4096 + j];
            s += bb1;
            hseg[b][t] = 0.5f * s * (1.0f + erff(s * 0.70710678118f));
        }
    }
    __syncthreads();
    int il = t & 63, ks = t >> 6;
    int i = ic * 64 + il;
    float acc[16] = {};
    for (int kk = 0; kk < 64; ++kk) {
        int kl = ks * 64 + kk;
        float wv = w2[(size_t)(kq * 256 + kl) * 1024 + i];
#pragma unroll
        for (int b = 0; b < 16; ++b) acc[b] += hseg[b][kl] * wv;
    }
#pragma unroll
    for (int b = 0; b < 16; ++b) red[ks][il][b] = acc[b];
    __syncthreads();
    int il2 = t & 63, bq = t >> 6;
#pragma unroll
    for (int bb = 0; bb < 4; ++bb) {
        int b = bq * 4 + bb;
        float s = red[0][il2][b] + red[1][il2][b] + red[2][il2][b] + red[3][il2][b];
        atomicAdd(&outp[(size_t)b * 1024 + ic * 64 + il2], s);
    }
}

// ---------------------------------------------------------------------------
extern "C" void kernel_launch(void* const* d_in, const int* in_sizes, int n_in,
                              void* d_out, int out_size, void* d_ws, size_t ws_size,
                              hipStream_t stream)
{
    const float* x        = (const float*)d_in[0];
    const float* state    = (const float*)d_in[1];
    const float* acc_ctx  = (const float*)d_in[2];
    const int*   fix_pt   = (const int*)d_in[3];
    const float* in_proj_w = (const float*)d_in[4];
    const float* in_proj_b = (const float*)d_in[5];
    const float* out_w    = (const float*)d_in[6];
    const float* out_b    = (const float*)d_in[7];
    const float* ln1_g    = (const float*)d_in[8];
    const float* ln1_b    = (const float*)d_in[9];
    const float* ln2_g    = (const float*)d_in[10];
    const float* ln2_b    = (const float*)d_in[11];
    const float* w1       = (const float*)d_in[12];
    const float* b1       = (const float*)d_in[13];
    const float* w2       = (const float*)d_in[14];
    const float* b2       = (const float*)d_in[15];
    float* outp = (float*)d_out;

    char* ws = (char*)d_ws;
    unsigned short* normed = (unsigned short*)ws; ws += (size_t)MPAD2 * DIM * 2;
    unsigned short* Wb     = (unsigned short*)ws; ws += (size_t)3072 * DIM * 2;
    unsigned short* kvb    = (unsigned short*)ws; ws += (size_t)MROWS * NKV * 2;
    float* ctx0    = (float*)ws; ws += (size_t)NB * DIM * 4;
    float* o_all   = (float*)ws; ws += (size_t)NB * DIM * 4;
    float* cls_pre = (float*)ws; ws += (size_t)NB * DIM * 4;
    float* ln2v    = (float*)ws; ws += (size_t)NB * DIM * 4;
    float* part    = (float*)ws; ws += (size_t)4 * 16 * 4096 * 4;

    float* newacc = outp + (size_t)NB * DIM;

    hipLaunchKernelGGL(build_ln_kernel, dim3(MPAD2), dim3(256), 0, stream,
                       x, state, acc_ctx, fix_pt, ln1_g, ln1_b, normed, ctx0, newacc);
    hipLaunchKernelGGL(convert_w_kernel, dim3(3072), dim3(256), 0, stream,
                       in_proj_w, Wb, 3072 * DIM / 4);
    hipLaunchKernelGGL(kv_gemm8_kernel, dim3(49, 8), dim3(512), 0, stream,
                       normed, Wb + (size_t)1024 * DIM, in_proj_b + 1024, kvb);
    hipLaunchKernelGGL(attn_kernel, dim3(256), dim3(256), 0, stream,
                       normed, Wb, in_proj_b, kvb, o_all);
    hipLaunchKernelGGL(out_proj_kernel, dim3(4096), dim3(256), 0, stream,
                       o_all, out_w, out_b, ctx0, cls_pre);
    hipLaunchKernelGGL(ln2_kernel, dim3(16), dim3(256), 0, stream,
                       cls_pre, ln2_g, ln2_b, b2, ln2v, outp);
    hipLaunchKernelGGL(mlp1p_kernel, dim3(64, 4), dim3(256), 0, stream,
                       ln2v, w1, part);
    hipLaunchKernelGGL(mlp2a_kernel, dim3(16, 16), dim3(256), 0, stream,
                       part, b1, w2, outp);
}

// Round 4
// 166.901 us; speedup vs baseline: 1.5048x; 1.3255x over previous
//
#include <hip/hip_runtime.h>
#include <hip/hip_bf16.h>
#include <math.h>

#define DIM 1024
#define NHEADS 16
#define HD 64
#define WIN 256
#define NB 16
#define NSEQ 4096
#define NACC 512
#define LCTX 769      // 1 + 512 + 256
#define MROWS 12304   // 16*769
#define MPAD2 12544   // 49*256
#define NKV 2048

typedef short bf16x8 __attribute__((ext_vector_type(8)));
typedef float f32x4 __attribute__((ext_vector_type(4)));

__device__ inline unsigned short f2b(float f) {
    union { float f; unsigned int u; } c; c.f = f;
    unsigned int u = c.u;
    u += 0x7FFFu + ((u >> 16) & 1u);
    return (unsigned short)(u >> 16);
}
__device__ inline float b2f(unsigned short h) {
    union { unsigned int u; float f; } c; c.u = ((unsigned int)h) << 16;
    return c.f;
}

// ---------------------------------------------------------------------------
// Kernel 1: build ctx rows, LN1 -> normed (bf16), write new_acc, save ctx row 0
// ---------------------------------------------------------------------------
__global__ __launch_bounds__(256) void build_ln_kernel(
    const float* __restrict__ x, const float* __restrict__ state,
    const float* __restrict__ acc_ctx, const int* __restrict__ fix_pt,
    const float* __restrict__ ln1_g, const float* __restrict__ ln1_b,
    unsigned short* __restrict__ normed, float* __restrict__ ctx0,
    float* __restrict__ newacc)
{
    int bid = blockIdx.x;
    int t = threadIdx.x;
    if (bid >= MROWS) {
        ushort4 z = make_ushort4(0, 0, 0, 0);
        ((ushort4*)(normed + (size_t)bid * DIM))[t] = z;
        return;
    }
    int b = bid / LCTX;
    int r = bid - b * LCTX;
    const float* src;
    if (r == 0) {
        src = state + (size_t)b * DIM;
    } else if (r <= NACC) {
        src = acc_ctx + ((size_t)b * NACC + (r - 1)) * DIM;
    } else {
        int fp = fix_pt[b];
        int start = fp - WIN / 2;
        if (start < 0) start = 0;
        if (start > NSEQ - WIN) start = NSEQ - WIN;
        src = x + ((size_t)b * NSEQ + start + (r - 1 - NACC)) * DIM;
    }
    float4 v = ((const float4*)src)[t];
    float s = v.x + v.y + v.z + v.w;
    float ss = v.x * v.x + v.y * v.y + v.z * v.z + v.w * v.w;
#pragma unroll
    for (int o = 32; o > 0; o >>= 1) { s += __shfl_down(s, o); ss += __shfl_down(ss, o); }
    __shared__ float rs[4], rss[4];
    int wid = t >> 6, lane = t & 63;
    if (lane == 0) { rs[wid] = s; rss[wid] = ss; }
    __syncthreads();
    float sum = rs[0] + rs[1] + rs[2] + rs[3];
    float sq  = rss[0] + rss[1] + rss[2] + rss[3];
    float mean = sum * (1.0f / DIM);
    float var = sq * (1.0f / DIM) - mean * mean;
    float rstd = rsqrtf(var + 1e-5f);
    float4 g  = ((const float4*)ln1_g)[t];
    float4 be = ((const float4*)ln1_b)[t];
    ushort4 nb;
    nb.x = f2b((v.x - mean) * rstd * g.x + be.x);
    nb.y = f2b((v.y - mean) * rstd * g.y + be.y);
    nb.z = f2b((v.z - mean) * rstd * g.z + be.z);
    nb.w = f2b((v.w - mean) * rstd * g.w + be.w);
    ((ushort4*)(normed + (size_t)bid * DIM))[t] = nb;
    if (r == 0) {
        ((float4*)(ctx0 + (size_t)b * DIM))[t] = v;
    } else {
        ((float4*)(newacc + ((size_t)b * (LCTX - 1) + (r - 1)) * DIM))[t] = v;
    }
}

// ---------------------------------------------------------------------------
// Kernel 2: convert in_proj_w (3072x1024 f32) -> bf16
// ---------------------------------------------------------------------------
__global__ __launch_bounds__(256) void convert_w_kernel(
    const float* __restrict__ w, unsigned short* __restrict__ wb, int n4)
{
    int idx = blockIdx.x * 256 + threadIdx.x;
    if (idx >= n4) return;
    float4 v = ((const float4*)w)[idx];
    ushort4 o;
    o.x = f2b(v.x); o.y = f2b(v.y); o.z = f2b(v.z); o.w = f2b(v.w);
    ((ushort4*)wb)[idx] = o;
}

// ---------------------------------------------------------------------------
// Kernel 3: KV GEMM, 256x256 tile, BK=64, 8 waves, 8-phase schedule
// ---------------------------------------------------------------------------
__device__ inline void stage_half(const unsigned short* __restrict__ g,
                                  unsigned short* l, int t)
{
    {
        int r = t >> 3, c8 = (t & 7) ^ (r & 7);
        __builtin_amdgcn_global_load_lds(
            (const __attribute__((address_space(1))) void*)(g + (size_t)r * 1024 + c8 * 8),
            (__attribute__((address_space(3))) void*)(l + (size_t)t * 8), 16, 0, 0);
    }
    {
        int t2 = t + 512;
        int r = t2 >> 3, c8 = (t2 & 7) ^ (r & 7);
        __builtin_amdgcn_global_load_lds(
            (const __attribute__((address_space(1))) void*)(g + (size_t)r * 1024 + c8 * 8),
            (__attribute__((address_space(3))) void*)(l + (size_t)t2 * 8), 16, 0, 0);
    }
}

__device__ inline bf16x8 ldsw(const unsigned short* h, int r, int c8)
{
    int slot = r * 8 + (c8 ^ (r & 7));
    return *(const bf16x8*)(h + slot * 8);
}

__global__ __launch_bounds__(512, 2) void kv_gemm8_kernel(
    const unsigned short* __restrict__ A,
    const unsigned short* __restrict__ Bw,
    const float* __restrict__ bias,
    unsigned short* __restrict__ C)
{
    __shared__ unsigned short sh[2][2][2][128 * 64];
    const int mt = blockIdx.x, nt = blockIdx.y;
    const int t = threadIdx.x;
    const int wid = t >> 6, lane = t & 63;
    const int wm = wid >> 2, wn = wid & 3;
    const int l15 = lane & 15, l16 = lane >> 4;
    const int rB = (wn & 1) * 64;
    const unsigned short* Abase = A + (size_t)mt * 256 * 1024;
    const unsigned short* Bbase = Bw + (size_t)nt * 256 * 1024;

    f32x4 acc[8][4] = {};
    bf16x8 a[4][2], b[4][2];

    stage_half(Abase,                   &sh[0][0][0][0], t);
    stage_half(Abase + 128 * 1024,      &sh[0][0][1][0], t);
    stage_half(Bbase,                   &sh[0][1][0][0], t);
    stage_half(Bbase + 128 * 1024,      &sh[0][1][1][0], t);
    stage_half(Bbase + 64,              &sh[1][1][0][0], t);
    stage_half(Bbase + 128 * 1024 + 64, &sh[1][1][1][0], t);
    asm volatile("s_waitcnt vmcnt(4)" ::: "memory");
    __builtin_amdgcn_s_barrier();

    auto ktile = [&](int T, bool stA, bool stB, bool steady) {
        const int d = T & 1;
        const unsigned short* AH = &sh[d][0][wm][0];
        const unsigned short* BH = &sh[d][1][wn >> 1][0];
        const int kA = (T + 1) * 64;
        const int kB = (T + 2) * 64;

#pragma unroll
        for (int i = 0; i < 4; ++i) {
            a[i][0] = ldsw(AH, i * 16 + l15, l16);
            a[i][1] = ldsw(AH, i * 16 + l15, 4 + l16);
        }
#pragma unroll
        for (int j = 0; j < 2; ++j) {
            b[j][0] = ldsw(BH, rB + j * 16 + l15, l16);
            b[j][1] = ldsw(BH, rB + j * 16 + l15, 4 + l16);
        }
        if (stA) stage_half(Abase + kA, &sh[d ^ 1][0][0][0], t);
        __builtin_amdgcn_sched_barrier(0);
        __builtin_amdgcn_s_barrier();
        asm volatile("s_waitcnt lgkmcnt(0)" ::: "memory");
        __builtin_amdgcn_sched_barrier(0);
        __builtin_amdgcn_s_setprio(1);
#pragma unroll
        for (int i = 0; i < 4; ++i)
#pragma unroll
            for (int j = 0; j < 2; ++j) {
                acc[i][j] = __builtin_amdgcn_mfma_f32_16x16x32_bf16(a[i][0], b[j][0], acc[i][j], 0, 0, 0);
                acc[i][j] = __builtin_amdgcn_mfma_f32_16x16x32_bf16(a[i][1], b[j][1], acc[i][j], 0, 0, 0);
            }
        __builtin_amdgcn_s_setprio(0);
        __builtin_amdgcn_sched_barrier(0);
        __builtin_amdgcn_s_barrier();

#pragma unroll
        for (int j = 2; j < 4; ++j) {
            b[j][0] = ldsw(BH, rB + j * 16 + l15, l16);
            b[j][1] = ldsw(BH, rB + j * 16 + l15, 4 + l16);
        }
        if (stA) stage_half(Abase + 128 * 1024 + kA, &sh[d ^ 1][0][1][0], t);
        __builtin_amdgcn_sched_barrier(0);
        __builtin_amdgcn_s_barrier();
        asm volatile("s_waitcnt lgkmcnt(0)" ::: "memory");
        __builtin_amdgcn_sched_barrier(0);
        __builtin_amdgcn_s_setprio(1);
#pragma unroll
        for (int i = 0; i < 4; ++i)
#pragma unroll
            for (int j = 2; j < 4; ++j) {
                acc[i][j] = __builtin_amdgcn_mfma_f32_16x16x32_bf16(a[i][0], b[j][0], acc[i][j], 0, 0, 0);
                acc[i][j] = __builtin_amdgcn_mfma_f32_16x16x32_bf16(a[i][1], b[j][1], acc[i][j], 0, 0, 0);
            }
        __builtin_amdgcn_s_setprio(0);
        __builtin_amdgcn_sched_barrier(0);
        __builtin_amdgcn_s_barrier();

#pragma unroll
        for (int i = 0; i < 4; ++i) {
            a[i][0] = ldsw(AH, 64 + i * 16 + l15, l16);
            a[i][1] = ldsw(AH, 64 + i * 16 + l15, 4 + l16);
        }
        if (stB) stage_half(Bbase + kB, &sh[d][1][0][0], t);
        __builtin_amdgcn_sched_barrier(0);
        __builtin_amdgcn_s_barrier();
        asm volatile("s_waitcnt lgkmcnt(0)" ::: "memory");
        __builtin_amdgcn_sched_barrier(0);
        __builtin_amdgcn_s_setprio(1);
#pragma unroll
        for (int i = 0; i < 4; ++i)
#pragma unroll
            for (int j = 0; j < 2; ++j) {
                acc[4 + i][j] = __builtin_amdgcn_mfma_f32_16x16x32_bf16(a[i][0], b[j][0], acc[4 + i][j], 0, 0, 0);
                acc[4 + i][j] = __builtin_amdgcn_mfma_f32_16x16x32_bf16(a[i][1], b[j][1], acc[4 + i][j], 0, 0, 0);
            }
        __builtin_amdgcn_s_setprio(0);
        __builtin_amdgcn_sched_barrier(0);
        __builtin_amdgcn_s_barrier();

        if (stB) stage_half(Bbase + 128 * 1024 + kB, &sh[d][1][1][0], t);
        __builtin_amdgcn_sched_barrier(0);
        __builtin_amdgcn_s_barrier();
        asm volatile("s_waitcnt lgkmcnt(0)" ::: "memory");
        __builtin_amdgcn_sched_barrier(0);
        __builtin_amdgcn_s_setprio(1);
#pragma unroll
        for (int i = 0; i < 4; ++i)
#pragma unroll
            for (int j = 2; j < 4; ++j) {
                acc[4 + i][j] = __builtin_amdgcn_mfma_f32_16x16x32_bf16(a[i][0], b[j][0], acc[4 + i][j], 0, 0, 0);
                acc[4 + i][j] = __builtin_amdgcn_mfma_f32_16x16x32_bf16(a[i][1], b[j][1], acc[4 + i][j], 0, 0, 0);
            }
        __builtin_amdgcn_s_setprio(0);
        if (steady) {
            asm volatile("s_waitcnt vmcnt(4)" ::: "memory");
        } else {
            asm volatile("s_waitcnt vmcnt(0)" ::: "memory");
        }
        __builtin_amdgcn_sched_barrier(0);
        __builtin_amdgcn_s_barrier();
    };

    for (int T = 0; T < 14; ++T) ktile(T, true, true, true);
    ktile(14, true, false, false);
    ktile(15, false, false, false);

#pragma unroll
    for (int i = 0; i < 8; ++i) {
        int gmb = mt * 256 + wm * 128 + i * 16 + l16 * 4;
#pragma unroll
        for (int j = 0; j < 4; ++j) {
            int gn = nt * 256 + wn * 64 + j * 16 + l15;
            float bs = bias[gn];
#pragma unroll
            for (int r = 0; r < 4; ++r) {
                int gm = gmb + r;
                if (gm < MROWS) C[(size_t)gm * NKV + gn] = f2b(acc[i][j][r] + bs);
            }
        }
    }
}

// ---------------------------------------------------------------------------
// Kernel 4: attention decode with fused q-projection, one block per (b,h)
// 512 threads (8 waves = 2/SIMD); vectorized PV (8 rows x 8 d-octets / wave)
// ---------------------------------------------------------------------------
__global__ __launch_bounds__(512) void attn_kernel(
    const unsigned short* __restrict__ normed,
    const unsigned short* __restrict__ Wq, const float* __restrict__ bq,
    const unsigned short* __restrict__ kv, float* __restrict__ o_all)
{
    int b = blockIdx.x >> 4, h = blockIdx.x & 15;
    int t = threadIdx.x;
    int wave = t >> 6, lane = t & 63;
    __shared__ float qs[64];
    __shared__ float sc[LCTX];
    __shared__ float red1[8], red2[8];
    __shared__ float po[8][64];

    // --- fused q projection: 8 waves x 8 outputs ---
    {
        const unsigned short* nr = normed + (size_t)(b * LCTX) * DIM;
        bf16x8 n0 = *(const bf16x8*)(nr + lane * 16);
        bf16x8 n1 = *(const bf16x8*)(nr + lane * 16 + 8);
#pragma unroll
        for (int jj = 0; jj < 8; ++jj) {
            int d = wave * 8 + jj;
            const unsigned short* wr = Wq + (size_t)(h * 64 + d) * DIM;
            bf16x8 w0 = *(const bf16x8*)(wr + lane * 16);
            bf16x8 w1 = *(const bf16x8*)(wr + lane * 16 + 8);
            float s = 0.f;
#pragma unroll
            for (int u = 0; u < 8; ++u)
                s += b2f((unsigned short)n0[u]) * b2f((unsigned short)w0[u]);
#pragma unroll
            for (int u = 0; u < 8; ++u)
                s += b2f((unsigned short)n1[u]) * b2f((unsigned short)w1[u]);
#pragma unroll
            for (int o = 32; o > 0; o >>= 1) s += __shfl_down(s, o);
            if (lane == 0) qs[d] = s + bq[h * 64 + d];
        }
    }
    __syncthreads();

    // --- QK^T scores: 769 keys striped over 512 threads (2 iters) ---
    float lmax = -1e30f;
    for (int l = t; l < LCTX; l += 512) {
        const unsigned short* kr = kv + ((size_t)(b * LCTX + l)) * NKV + h * 64;
        const uint4* k4 = (const uint4*)kr;
        float s = 0.f;
#pragma unroll
        for (int c = 0; c < 8; ++c) {
            uint4 u = k4[c];
            s += qs[c * 8 + 0] * b2f((unsigned short)(u.x & 0xffffu));
            s += qs[c * 8 + 1] * b2f((unsigned short)(u.x >> 16));
            s += qs[c * 8 + 2] * b2f((unsigned short)(u.y & 0xffffu));
            s += qs[c * 8 + 3] * b2f((unsigned short)(u.y >> 16));
            s += qs[c * 8 + 4] * b2f((unsigned short)(u.z & 0xffffu));
            s += qs[c * 8 + 5] * b2f((unsigned short)(u.z >> 16));
            s += qs[c * 8 + 6] * b2f((unsigned short)(u.w & 0xffffu));
            s += qs[c * 8 + 7] * b2f((unsigned short)(u.w >> 16));
        }
        s *= 0.125f;
        sc[l] = s;
        lmax = fmaxf(lmax, s);
    }
#pragma unroll
    for (int o = 32; o > 0; o >>= 1) lmax = fmaxf(lmax, __shfl_down(lmax, o));
    if (lane == 0) red1[wave] = lmax;
    __syncthreads();
    float m = red1[0];
#pragma unroll
    for (int w8 = 1; w8 < 8; ++w8) m = fmaxf(m, red1[w8]);

    float lsum = 0.f;
    for (int l = t; l < LCTX; l += 512) {
        float p = __expf(sc[l] - m);
        sc[l] = p;
        lsum += p;
    }
#pragma unroll
    for (int o = 32; o > 0; o >>= 1) lsum += __shfl_down(lsum, o);
    if (lane == 0) red2[wave] = lsum;
    __syncthreads();
    float S = 0.f;
#pragma unroll
    for (int w8 = 0; w8 < 8; ++w8) S += red2[w8];

    // --- PV: wave handles 8 rows/iter, lane = (row-subgroup, d-octet) ---
    int rg = lane >> 3;        // 0..7 row subgroup
    int dc = (lane & 7) * 8;   // d-octet start
    float acc[8] = {};
    for (int it = 0; it < 13; ++it) {
        int row = it * 64 + wave * 8 + rg;
        if (row < LCTX) {
            const unsigned short* vr =
                kv + ((size_t)(b * LCTX + row)) * NKV + 1024 + h * 64 + dc;
            bf16x8 v = *(const bf16x8*)vr;
            float p = sc[row];
#pragma unroll
            for (int u = 0; u < 8; ++u) acc[u] += p * b2f((unsigned short)v[u]);
        }
    }
#pragma unroll
    for (int u = 0; u < 8; ++u) {
        acc[u] += __shfl_xor(acc[u], 8);
        acc[u] += __shfl_xor(acc[u], 16);
        acc[u] += __shfl_xor(acc[u], 32);
    }
    if (rg == 0) {
#pragma unroll
        for (int u = 0; u < 8; ++u) po[wave][dc + u] = acc[u];
    }
    __syncthreads();
    if (t < 64) {
        float o = 0.f;
#pragma unroll
        for (int w8 = 0; w8 < 8; ++w8) o += po[w8][t];
        o_all[b * 1024 + h * 64 + t] = o / S;
    }
}

// ---------------------------------------------------------------------------
// Kernel 5: cls_pre[b,i] = ctx0[b,i] + sum_j o_all[b,j]*out_w[i,j] + out_b[i]
// ---------------------------------------------------------------------------
__global__ __launch_bounds__(256) void out_proj_kernel(
    const float* __restrict__ o_all, const float* __restrict__ out_w,
    const float* __restrict__ out_b, const float* __restrict__ ctx0,
    float* __restrict__ cls_pre)
{
    int gw = blockIdx.x * 4 + (threadIdx.x >> 6);
    int lane = threadIdx.x & 63;
    int b = gw >> 10, i = gw & 1023;
    const float* orow = o_all + (size_t)b * 1024;
    const float* wrow = out_w + (size_t)i * 1024;
    float s = 0.f;
#pragma unroll
    for (int kk = 0; kk < 16; ++kk) {
        int k = kk * 64 + lane;
        s += orow[k] * wrow[k];
    }
#pragma unroll
    for (int o = 32; o > 0; o >>= 1) s += __shfl_down(s, o);
    if (lane == 0) cls_pre[gw] = ctx0[gw] + s + out_b[i];
}

// ---------------------------------------------------------------------------
// Kernel 6: LN2 over cls_pre rows; also init outp = cls_pre + b2
// ---------------------------------------------------------------------------
__global__ __launch_bounds__(256) void ln2_kernel(
    const float* __restrict__ cls_pre, const float* __restrict__ g,
    const float* __restrict__ be, const float* __restrict__ b2,
    float* __restrict__ ln2o, float* __restrict__ outp)
{
    int b = blockIdx.x, t = threadIdx.x;
    float4 v = ((const float4*)(cls_pre + (size_t)b * DIM))[t];
    float s = v.x + v.y + v.z + v.w;
    float ss = v.x * v.x + v.y * v.y + v.z * v.z + v.w * v.w;
#pragma unroll
    for (int o = 32; o > 0; o >>= 1) { s += __shfl_down(s, o); ss += __shfl_down(ss, o); }
    __shared__ float rs[4], rss[4];
    int wid = t >> 6, lane = t & 63;
    if (lane == 0) { rs[wid] = s; rss[wid] = ss; }
    __syncthreads();
    float sum = rs[0] + rs[1] + rs[2] + rs[3];
    float sq  = rss[0] + rss[1] + rss[2] + rss[3];
    float mean = sum * (1.0f / DIM);
    float var = sq * (1.0f / DIM) - mean * mean;
    float rstd = rsqrtf(var + 1e-5f);
    float4 gv = ((const float4*)g)[t];
    float4 bv = ((const float4*)be)[t];
    float4 o;
    o.x = (v.x - mean) * rstd * gv.x + bv.x;
    o.y = (v.y - mean) * rstd * gv.y + bv.y;
    o.z = (v.z - mean) * rstd * gv.z + bv.z;
    o.w = (v.w - mean) * rstd * gv.w + bv.w;
    ((float4*)(ln2o + (size_t)b * DIM))[t] = o;
    float4 b2v = ((const float4*)b2)[t];
    float4 oi;
    oi.x = v.x + b2v.x; oi.y = v.y + b2v.y; oi.z = v.z + b2v.z; oi.w = v.w + b2v.w;
    ((float4*)(outp + (size_t)b * DIM))[t] = oi;
}

// ---------------------------------------------------------------------------
// Kernel 7: mlp1 partials: part[kq][b][j] = sum_{k in kq-range} ln2[b,k]*w1[k,j]
// ---------------------------------------------------------------------------
__global__ __launch_bounds__(256) void mlp1p_kernel(
    const float* __restrict__ ln2v, const float* __restrict__ w1,
    float* __restrict__ part)
{
    __shared__ float l2s[16][256];
    __shared__ float red[4][64][16];
    int jc = blockIdx.x, kq = blockIdx.y;
    int t = threadIdx.x;
#pragma unroll
    for (int b = 0; b < 16; ++b)
        l2s[b][t] = ln2v[(size_t)b * 1024 + kq * 256 + t];
    __syncthreads();
    int jl = t & 63, ks = t >> 6;
    int j = jc * 64 + jl;
    float acc[16] = {};
    for (int kk = 0; kk < 64; ++kk) {
        int kl = ks * 64 + kk;
        float wv = w1[(size_t)(kq * 256 + kl) * 4096 + j];
#pragma unroll
        for (int b = 0; b < 16; ++b) acc[b] += l2s[b][kl] * wv;
    }
#pragma unroll
    for (int b = 0; b < 16; ++b) red[ks][jl][b] = acc[b];
    __syncthreads();
    int jl2 = t & 63, bq = t >> 6;
#pragma unroll
    for (int bb = 0; bb < 4; ++bb) {
        int b = bq * 4 + bb;
        float s = red[0][jl2][b] + red[1][jl2][b] + red[2][jl2][b] + red[3][jl2][b];
        part[((size_t)kq * 16 + b) * 4096 + jc * 64 + jl2] = s;
    }
}

// ---------------------------------------------------------------------------
// Kernel 8: mlp2 with in-LDS reduce+gelu of mlp1 partials, atomicAdd to outp
// ---------------------------------------------------------------------------
__global__ __launch_bounds__(256) void mlp2a_kernel(
    const float* __restrict__ part, const float* __restrict__ b1,
    const float* __restrict__ w2, float* __restrict__ outp)
{
    __shared__ float hseg[16][256];
    __shared__ float red[4][64][16];
    int ic = blockIdx.x, kq = blockIdx.y;
    int t = threadIdx.x;
    {
        int j = kq * 256 + t;
        float bb1 = b1[j];
#pragma unroll
        for (int b = 0; b < 16; ++b) {
            float s = part[((size_t)0 * 16 + b) * 4096 + j]
                    + part[((size_t)1 * 16 + b) * 4096 + j]
                    + part[((size_t)2 * 16 + b) * 4096 + j]
                    + part[((size_t)3 * 16 + b) * 4096 + j];
            s += bb1;
            hseg[b][t] = 0.5f * s * (1.0f + erff(s * 0.70710678118f));
        }
    }
    __syncthreads();
    int il = t & 63, ks = t >> 6;
    int i = ic * 64 + il;
    float acc[16] = {};
    for (int kk = 0; kk < 64; ++kk) {
        int kl = ks * 64 + kk;
        float wv = w2[(size_t)(kq * 256 + kl) * 1024 + i];
#pragma unroll
        for (int b = 0; b < 16; ++b) acc[b] += hseg[b][kl] * wv;
    }
#pragma unroll
    for (int b = 0; b < 16; ++b) red[ks][il][b] = acc[b];
    __syncthreads();
    int il2 = t & 63, bq = t >> 6;
#pragma unroll
    for (int bb = 0; bb < 4; ++bb) {
        int b = bq * 4 + bb;
        float s = red[0][il2][b] + red[1][il2][b] + red[2][il2][b] + red[3][il2][b];
        atomicAdd(&outp[(size_t)b * 1024 + ic * 64 + il2], s);
    }
}

// ---------------------------------------------------------------------------
extern "C" void kernel_launch(void* const* d_in, const int* in_sizes, int n_in,
                              void* d_out, int out_size, void* d_ws, size_t ws_size,
                              hipStream_t stream)
{
    const float* x        = (const float*)d_in[0];
    const float* state    = (const float*)d_in[1];
    const float* acc_ctx  = (const float*)d_in[2];
    const int*   fix_pt   = (const int*)d_in[3];
    const float* in_proj_w = (const float*)d_in[4];
    const float* in_proj_b = (const float*)d_in[5];
    const float* out_w    = (const float*)d_in[6];
    const float* out_b    = (const float*)d_in[7];
    const float* ln1_g    = (const float*)d_in[8];
    const float* ln1_b    = (const float*)d_in[9];
    const float* ln2_g    = (const float*)d_in[10];
    const float* ln2_b    = (const float*)d_in[11];
    const float* w1       = (const float*)d_in[12];
    const float* b1       = (const float*)d_in[13];
    const float* w2       = (const float*)d_in[14];
    const float* b2       = (const float*)d_in[15];
    float* outp = (float*)d_out;

    char* ws = (char*)d_ws;
    unsigned short* normed = (unsigned short*)ws; ws += (size_t)MPAD2 * DIM * 2;
    unsigned short* Wb     = (unsigned short*)ws; ws += (size_t)3072 * DIM * 2;
    unsigned short* kvb    = (unsigned short*)ws; ws += (size_t)MROWS * NKV * 2;
    float* ctx0    = (float*)ws; ws += (size_t)NB * DIM * 4;
    float* o_all   = (float*)ws; ws += (size_t)NB * DIM * 4;
    float* cls_pre = (float*)ws; ws += (size_t)NB * DIM * 4;
    float* ln2v    = (float*)ws; ws += (size_t)NB * DIM * 4;
    float* part    = (float*)ws; ws += (size_t)4 * 16 * 4096 * 4;

    float* newacc = outp + (size_t)NB * DIM;

    hipLaunchKernelGGL(build_ln_kernel, dim3(MPAD2), dim3(256), 0, stream,
                       x, state, acc_ctx, fix_pt, ln1_g, ln1_b, normed, ctx0, newacc);
    hipLaunchKernelGGL(convert_w_kernel, dim3(3072), dim3(256), 0, stream,
                       in_proj_w, Wb, 3072 * DIM / 4);
    hipLaunchKernelGGL(kv_gemm8_kernel, dim3(49, 8), dim3(512), 0, stream,
                       normed, Wb + (size_t)1024 * DIM, in_proj_b + 1024, kvb);
    hipLaunchKernelGGL(attn_kernel, dim3(256), dim3(512), 0, stream,
                       normed, Wb, in_proj_b, kvb, o_all);
    hipLaunchKernelGGL(out_proj_kernel, dim3(4096), dim3(256), 0, stream,
                       o_all, out_w, out_b, ctx0, cls_pre);
    hipLaunchKernelGGL(ln2_kernel, dim3(16), dim3(256), 0, stream,
                       cls_pre, ln2_g, ln2_b, b2, ln2v, outp);
    hipLaunchKernelGGL(mlp1p_kernel, dim3(64, 4), dim3(256), 0, stream,
                       ln2v, w1, part);
    hipLaunchKernelGGL(mlp2a_kernel, dim3(16, 16), dim3(256), 0, stream,
                       part, b1, w2, outp);
}